// Round 16
// baseline (854.435 us; speedup 1.0000x reference)
//
#include <hip/hip_runtime.h>
#include <hip/hip_bf16.h>

typedef __attribute__((ext_vector_type(8))) short bf16x8;
typedef __attribute__((ext_vector_type(4))) float f32x4;

__device__ __forceinline__ float bf2f(unsigned short u) {
    union { unsigned int i; float f; } v; v.i = ((unsigned int)u) << 16; return v.f;
}
__device__ __forceinline__ unsigned short f2bf(float f) {
    union { float f; unsigned int i; } v; v.f = f;
    unsigned int x = v.i;
    return (unsigned short)((x + 0x7FFFu + ((x >> 16) & 1u)) >> 16);
}

__device__ __forceinline__ void gload_lds16(const unsigned short* g, unsigned short* l) {
    __builtin_amdgcn_global_load_lds(
        (const __attribute__((address_space(1))) unsigned int*)g,
        (__attribute__((address_space(3))) unsigned int*)l,
        16, 0, 0);
}

#define VM8  asm volatile("s_waitcnt vmcnt(8)" ::: "memory")
#define VM0  asm volatile("s_waitcnt vmcnt(0)" ::: "memory")
#define SB0  __builtin_amdgcn_sched_barrier(0)
#define BAR  __builtin_amdgcn_s_barrier()

// ---------------------------------------------------------------------------
// concat(motion, command) -> bf16 [8192, 576]
// ---------------------------------------------------------------------------
__global__ void concat_cvt(const float* __restrict__ motion,
                           const float* __restrict__ command,
                           unsigned short* __restrict__ out) {
    int id = blockIdx.x * 256 + threadIdx.x;
    int b = id / 144, q = id % 144;
    float4 v;
    if (q < 128) v = *(const float4*)(motion + (size_t)b * 512 + q * 4);
    else         v = *(const float4*)(command + (size_t)b * 64 + (q - 128) * 4);
    ushort4 o;
    o.x = f2bf(v.x); o.y = f2bf(v.y); o.z = f2bf(v.z); o.w = f2bf(v.w);
    *(ushort4*)(out + (size_t)b * 576 + q * 4) = o;
}

// ---------------------------------------------------------------------------
// batched fp32 [K,N] -> bf16 [N,K] per expert (tpe = 64x64 tiles per expert)
// ---------------------------------------------------------------------------
__global__ void transpose_cvt(const float* __restrict__ in,
                              unsigned short* __restrict__ out,
                              int K, int N, int tpe) {
    __shared__ unsigned short tile[64][72];
    int e = blockIdx.x / tpe, r = blockIdx.x % tpe;
    in  += (size_t)e * K * N;
    out += (size_t)e * N * K;
    int nbn = N / 64;
    int k0 = (r / nbn) * 64;
    int n0 = (r % nbn) * 64;
    int t = threadIdx.x;
    int tx = t & 63, ty = t >> 6;
    #pragma unroll
    for (int rr = 0; rr < 16; ++rr) {
        int kr = ty + rr * 4;
        tile[kr][tx] = f2bf(in[(size_t)(k0 + kr) * N + n0 + tx]);
    }
    __syncthreads();
    int txh = t & 31, tyh = t >> 5;
    #pragma unroll
    for (int rr = 0; rr < 8; ++rr) {
        int nr = tyh + rr * 8;
        unsigned int vlo = tile[2 * txh][nr];
        unsigned int vhi = tile[2 * txh + 1][nr];
        unsigned int* o32 = (unsigned int*)(out + (size_t)(n0 + nr) * K + k0);
        o32[txh] = vlo | (vhi << 16);
    }
}

// ---------------------------------------------------------------------------
// gating final: coeffs = softmax(g2 @ w3 + b3)
// ---------------------------------------------------------------------------
__global__ __launch_bounds__(256) void gating_kernel(
    const unsigned short* __restrict__ g2,
    const float* __restrict__ w3, const float* __restrict__ b3,
    float* __restrict__ coeffs) {
    __shared__ float w3s[8][1024];
    int t = threadIdx.x;
    for (int i = t; i < 1024; i += 256) {
        #pragma unroll
        for (int e = 0; e < 8; ++e) w3s[e][i] = w3[(size_t)i * 8 + e];
    }
    __syncthreads();
    int lane = t & 63, wv = t >> 6;
    int row = blockIdx.x * 4 + wv;
    const unsigned short* xr = g2 + (size_t)row * 1024;
    float acc[8];
    #pragma unroll
    for (int e = 0; e < 8; ++e) acc[e] = 0.f;
    for (int it = 0; it < 16; ++it) {
        float xv = bf2f(xr[lane + it * 64]);
        #pragma unroll
        for (int e = 0; e < 8; ++e) acc[e] += xv * w3s[e][lane + it * 64];
    }
    #pragma unroll
    for (int e = 0; e < 8; ++e) {
        float v = acc[e];
        #pragma unroll
        for (int off = 32; off; off >>= 1) v += __shfl_xor(v, off);
        acc[e] = v + b3[e];
    }
    float mx = acc[0];
    #pragma unroll
    for (int e = 1; e < 8; ++e) mx = fmaxf(mx, acc[e]);
    float s = 0.f;
    #pragma unroll
    for (int e = 0; e < 8; ++e) { acc[e] = __expf(acc[e] - mx); s += acc[e]; }
    float inv = 1.f / s;
    if (lane < 8) coeffs[(size_t)row * 8 + lane] = acc[lane] * inv;
}

// ---------------------------------------------------------------------------
// gating GEMM (proven): 128x128x64, global_load_lds both operands, 4 blk/CU
// ---------------------------------------------------------------------------
template<bool DO_ELU>
__global__ __launch_bounds__(256, 4)
void gemm_bf16(const unsigned short* __restrict__ A,
               const unsigned short* __restrict__ BT,
               const float* __restrict__ bias,
               unsigned short* __restrict__ Out,
               int N, int ld, int kpart) {
    __shared__ unsigned short As[128 * 64];
    __shared__ unsigned short Bs[128 * 64];
    int ntn = N >> 7;
    int nwg = gridDim.x;
    int bid = blockIdx.x;
    { int cpx = nwg >> 3; bid = (bid & 7) * cpx + (bid >> 3); }
    int tm = bid / ntn, tn = bid - tm * ntn;
    int row0 = tm << 7, col0 = tn << 7;
    int t = threadIdx.x;
    int lane = t & 63;
    int wid = t >> 6;
    int wr = wid >> 1, wc = wid & 1;
    const unsigned short* Ab = A + (size_t)(row0 + wid * 32 + (lane >> 3)) * ld + (lane & 7) * 8;
    const unsigned short* Bb = BT + (size_t)(col0 + wid * 32 + (lane >> 3)) * ld + (lane & 7) * 8;
    unsigned short* Asd = &As[wid * 32 * 64];
    unsigned short* Bsd = &Bs[wid * 32 * 64];
    f32x4 acc[4][4];
    #pragma unroll
    for (int i = 0; i < 4; ++i)
        #pragma unroll
        for (int j = 0; j < 4; ++j) acc[i][j] = (f32x4){0.f, 0.f, 0.f, 0.f};
    int nkt = kpart >> 6;
    for (int kt = 0; kt < nkt; ++kt) {
        size_t ko = (size_t)kt << 6;
        #pragma unroll
        for (int q = 0; q < 4; ++q) {
            gload_lds16(Ab + (size_t)(q * 8) * ld + ko, Asd + q * 8 * 64);
            gload_lds16(Bb + (size_t)(q * 8) * ld + ko, Bsd + q * 8 * 64);
        }
        __syncthreads();
        #pragma unroll
        for (int kk = 0; kk < 2; ++kk) {
            bf16x8 af[4], bfr[4];
            #pragma unroll
            for (int m = 0; m < 4; ++m)
                af[m] = *(const bf16x8*)(&As[(wr * 64 + m * 16 + (lane & 15)) * 64 + kk * 32 + (lane >> 4) * 8]);
            #pragma unroll
            for (int n = 0; n < 4; ++n)
                bfr[n] = *(const bf16x8*)(&Bs[(wc * 64 + n * 16 + (lane & 15)) * 64 + kk * 32 + (lane >> 4) * 8]);
            #pragma unroll
            for (int m = 0; m < 4; ++m)
                #pragma unroll
                for (int n = 0; n < 4; ++n)
                    acc[m][n] = __builtin_amdgcn_mfma_f32_16x16x32_bf16(af[m], bfr[n], acc[m][n], 0, 0, 0);
        }
        __syncthreads();
    }
    #pragma unroll
    for (int m = 0; m < 4; ++m) {
        int rbase = row0 + wr * 64 + m * 16 + ((lane >> 4) << 2);
        #pragma unroll
        for (int n = 0; n < 4; ++n) {
            int cg = col0 + wc * 64 + n * 16 + (lane & 15);
            float bv = bias[cg];
            #pragma unroll
            for (int r2 = 0; r2 < 4; ++r2) {
                float v = acc[m][n][r2] + bv;
                if (DO_ELU) v = v > 0.f ? v : (__expf(v) - 1.f);
                Out[(size_t)(rbase + r2) * N + cg] = f2bf(v);
            }
        }
    }
}

// ---------------------------------------------------------------------------
// Fused MoE GEMM (r14 base + RACE-FREE wave phase-stagger): 256x256-virtual
// tile, 8 waves (wave = 128x64v), BK=32 slots, 4-slot LDS ring (128 KB),
// swizzled staging/reads, swapped-operand MFMA. Per 2-slot iteration:
//   stage(s+2,s+3) -> VM8 -> BAR -> compute (staggered order) -> BAR
// End-BAR guarantees: stage at iter u targets buffers whose readers all
// passed the end-BAR of iter u-2 -- race-free for ANY compute order.
// Stagger: half the waves compute (s,s+1), other half (s+1,s) -> opposite-
// phase waves per SIMD overlap ds_read with MFMA (T5 prerequisite).
// 2D XCD map (r12 proven, FETCH 94 MB).
// Epilogue: in-register expert mix -> LDS fp32 partials -> y store direct.
// ---------------------------------------------------------------------------
template<bool DO_ELU, bool OUT_F32>
__global__ __launch_bounds__(512, 1)
void gemm_fused(const unsigned short* __restrict__ A,   // [8192, K]
                const unsigned short* __restrict__ BT,  // [8*dout, K]
                const float* __restrict__ coeffs,       // [8192, 8]
                const float* __restrict__ bias,         // [8*dout]
                void* __restrict__ Out,                 // [8192, dout]
                int K, int dout) {
    __shared__ unsigned short lds[65536];           // 4 x (A 8192 + B 8192)

    // 2D concurrency-aware XCD mapping (r12 proven)
    int bid = blockIdx.x;
    int x = bid & 7;
    int i = bid >> 3;
    int within = i & 15;
    int tm = x * 4 + (within & 3);
    int tn = (i >> 4) * 4 + (within >> 2);
    int row0 = tm << 8;
    int c0 = tn << 5;
    int nkt = K >> 5;

    int t = threadIdx.x;
    int lane = t & 63, wid = t >> 6;
    int wm = wid >> 2, wn = wid & 3;                 // 2x4 waves, each 128x64
    int q = lane >> 4;
    int l15 = lane & 15;
    int grp = ((wid >> 2) ^ wid) & 1;                // opposite per SIMD-pair

    // fragment ds_read offsets (ushort units), swizzled
    int aoff[8], boff[4];
    #pragma unroll
    for (int m = 0; m < 8; ++m) {
        int row = wm * 128 + m * 16 + l15;
        aoff[m] = row * 32 + ((q ^ ((row >> 1) & 3)) << 3);
    }
    #pragma unroll
    for (int n = 0; n < 4; ++n) {
        int row = wn * 64 + n * 16 + l15;
        boff[n] = 8192 + row * 32 + ((q ^ ((row >> 1) & 3)) << 3);
    }

    // stage source (per-thread, inverse-swizzled column)
    int srow = t >> 2;
    int scol = ((t & 3) ^ ((t >> 3) & 3)) * 8;
    const unsigned short* Asrc = A + (size_t)(row0 + srow) * K + scol;
    // virtual B rows: vr -> BT row (vr>>5)*dout + c0 + (vr&31)
    int br0 = (srow >> 5) * dout + c0 + (srow & 31);            // vr = srow
    int br1 = ((srow + 128) >> 5) * dout + c0 + (srow & 31);    // vr = srow+128
    const unsigned short* Bsrc0 = BT + (size_t)br0 * K + scol;
    const unsigned short* Bsrc1 = BT + (size_t)br1 * K + scol;
    int wdst = wid * 512;                            // wave-uniform dest term

    f32x4 acc[8][4];
    #pragma unroll
    for (int m = 0; m < 8; ++m)
        #pragma unroll
        for (int n = 0; n < 4; ++n) acc[m][n] = (f32x4){0.f, 0.f, 0.f, 0.f};

    // ---- prologue: stage slots 0, 1 ----
    #pragma unroll
    for (int S = 0; S < 2; ++S) {
        gload_lds16(Asrc + S * 32,                   &lds[S * 16384 + wdst]);
        gload_lds16(Asrc + (size_t)128 * K + S * 32, &lds[S * 16384 + 4096 + wdst]);
        gload_lds16(Bsrc0 + S * 32,                  &lds[S * 16384 + 8192 + wdst]);
        gload_lds16(Bsrc1 + S * 32,                  &lds[S * 16384 + 12288 + wdst]);
    }

    auto compute_slot = [&](int sb) {
        bf16x8 bfrg[4], afr[8];
        #pragma unroll
        for (int n = 0; n < 4; ++n)
            bfrg[n] = *(const bf16x8*)(&lds[sb + boff[n]]);
        afr[0] = *(const bf16x8*)(&lds[sb + aoff[0]]);
        afr[1] = *(const bf16x8*)(&lds[sb + aoff[1]]);
        __builtin_amdgcn_s_setprio(1);
        #pragma unroll
        for (int m = 0; m < 8; ++m) {
            if (m + 2 < 8)
                afr[m + 2] = *(const bf16x8*)(&lds[sb + aoff[m + 2]]);
            #pragma unroll
            for (int n = 0; n < 4; ++n)
                acc[m][n] = __builtin_amdgcn_mfma_f32_16x16x32_bf16(bfrg[n], afr[m], acc[m][n], 0, 0, 0);
        }
        __builtin_amdgcn_s_setprio(0);
    };

    for (int s = 0; s < nkt; s += 2) {               // nkt even (18 or 32)
        int sbA = (s & 3) << 14;
        int sbB = ((s + 1) & 3) << 14;
        bool st = (s + 2) < nkt;

        // stage s+2, s+3 (targets bufs whose readers passed end-BAR of s-2)
        if (st) {
            int rbA = ((s + 2) & 3) << 14;
            int rbB = ((s + 3) & 3) << 14;
            int koA = (s + 2) << 5;
            int koB = (s + 3) << 5;
            gload_lds16(Asrc + koA,                   &lds[rbA + wdst]);
            gload_lds16(Asrc + (size_t)128 * K + koA, &lds[rbA + 4096 + wdst]);
            gload_lds16(Bsrc0 + koA,                  &lds[rbA + 8192 + wdst]);
            gload_lds16(Bsrc1 + koA,                  &lds[rbA + 12288 + wdst]);
            gload_lds16(Asrc + koB,                   &lds[rbB + wdst]);
            gload_lds16(Asrc + (size_t)128 * K + koB, &lds[rbB + 4096 + wdst]);
            gload_lds16(Bsrc0 + koB,                  &lds[rbB + 8192 + wdst]);
            gload_lds16(Bsrc1 + koB,                  &lds[rbB + 12288 + wdst]);
        }
        SB0;
        if (st) { VM8; } else { VM0; }               // drain s,s+1; keep s+2,s+3
        SB0;
        BAR;                                         // all waves' s,s+1 published
        SB0;

        // phase-staggered slot order: opposite-phase waves per SIMD
        if (grp == 0) {
            compute_slot(sbA);
            compute_slot(sbB);
        } else {
            compute_slot(sbB);
            compute_slot(sbA);
        }
        SB0;
        BAR;                                         // readers done before next stage
        SB0;
    }

    // ======== epilogue phase 1: per-wave expert mix -> LDS fp32 partials ===
    float* plds = (float*)lds;                       // 8 regions x [128][32] f32
    __syncthreads();                                 // ring fully consumed
    {
        int e0 = 2 * wn, e1 = e0 + 1;
        f32x4 b0h[2], b1h[2];
        #pragma unroll
        for (int h = 0; h < 2; ++h) {
            float4 u0 = *(const float4*)(bias + e0 * dout + c0 + h * 16 + q * 4);
            float4 u1 = *(const float4*)(bias + e1 * dout + c0 + h * 16 + q * 4);
            b0h[h] = (f32x4){u0.x, u0.y, u0.z, u0.w};
            b1h[h] = (f32x4){u1.x, u1.y, u1.z, u1.w};
        }
        float* preg = plds + (wid << 12);
        #pragma unroll
        for (int m = 0; m < 8; ++m) {
            int grow = row0 + wm * 128 + m * 16 + l15;
            float c8 = coeffs[(size_t)grow * 8 + e0];
            float c9 = coeffs[(size_t)grow * 8 + e1];
            #pragma unroll
            for (int h = 0; h < 2; ++h) {
                f32x4 z0 = acc[m][h];
                f32x4 z1 = acc[m][h + 2];
                f32x4 p;
                #pragma unroll
                for (int r = 0; r < 4; ++r)
                    p[r] = c8 * (z0[r] + b0h[h][r]) + c9 * (z1[r] + b1h[h][r]);
                int row = m * 16 + l15;
                int slot = (h * 4 + q) ^ (row & 7);
                *(f32x4*)(preg + row * 32 + (slot << 2)) = p;
            }
        }
    }
    __syncthreads();

    // ======== epilogue phase 2: sum 4 wn-partials, act, store ==============
    {
        int r2 = t >> 1;                             // tile row 0..255
        int ch = t & 1;                              // col half (16 cols)
        int wmr = r2 >> 7;
        int rr = r2 & 127;
        int sw = rr & 7;
        size_t obase = (size_t)(row0 + r2) * dout + c0 + ch * 16;
        #pragma unroll
        for (int sl = 0; sl < 4; ++sl) {
            int L = ch * 4 + sl;
            int phys = L ^ sw;
            f32x4 sum = (f32x4){0.f, 0.f, 0.f, 0.f};
            #pragma unroll
            for (int w2 = 0; w2 < 4; ++w2) {
                const f32x4 v = *(const f32x4*)(plds + (((wmr << 2) + w2) << 12) + rr * 32 + (phys << 2));
                sum[0] += v[0]; sum[1] += v[1]; sum[2] += v[2]; sum[3] += v[3];
            }
            if (DO_ELU) {
                #pragma unroll
                for (int r = 0; r < 4; ++r)
                    sum[r] = sum[r] > 0.f ? sum[r] : (__expf(sum[r]) - 1.f);
            }
            if (OUT_F32) {
                float4 o = {sum[0], sum[1], sum[2], sum[3]};
                *(float4*)((float*)Out + obase + sl * 4) = o;
            } else {
                ushort4 o;
                o.x = f2bf(sum[0]); o.y = f2bf(sum[1]);
                o.z = f2bf(sum[2]); o.w = f2bf(sum[3]);
                *(ushort4*)((unsigned short*)Out + obase + sl * 4) = o;
            }
        }
    }
}

// ---------------------------------------------------------------------------
extern "C" void kernel_launch(void* const* d_in, const int* in_sizes, int n_in,
                              void* d_out, int out_size, void* d_ws, size_t ws_size,
                              hipStream_t stream) {
    const float* motion  = (const float*)d_in[0];
    const float* command = (const float*)d_in[1];
    const float* g_w1 = (const float*)d_in[2];
    const float* g_b1 = (const float*)d_in[3];
    const float* g_w2 = (const float*)d_in[4];
    const float* g_b2 = (const float*)d_in[5];
    const float* g_w3 = (const float*)d_in[6];
    const float* g_b3 = (const float*)d_in[7];
    const float* w[6]  = {(const float*)d_in[8],  (const float*)d_in[10],
                          (const float*)d_in[12], (const float*)d_in[14],
                          (const float*)d_in[16], (const float*)d_in[18]};
    const float* bb[6] = {(const float*)d_in[9],  (const float*)d_in[11],
                          (const float*)d_in[13], (const float*)d_in[15],
                          (const float*)d_in[17], (const float*)d_in[19]};

    char* ws = (char*)d_ws;
    unsigned short* xc0  = (unsigned short*)ws;                 //  9,437,184
    unsigned short* actA = (unsigned short*)(ws + 9437184);     // 16,777,216
    unsigned short* actB = (unsigned short*)(ws + 26214400);    // 16,777,216
    float* coeffs        = (float*)(ws + 42991616);             //    262,144
    unsigned short* wT   = (unsigned short*)(ws + 43253760);    // 16,777,216

    // 1. concat + convert input
    concat_cvt<<<4608, 256, 0, stream>>>(motion, command, xc0);

    // 2. gating network
    transpose_cvt<<<144, 256, 0, stream>>>(g_w1, wT, 576, 1024, 144);
    gemm_bf16<true><<<512, 256, 0, stream>>>(xc0, wT, g_b1, actA, 1024, 576, 576);
    transpose_cvt<<<256, 256, 0, stream>>>(g_w2, wT, 1024, 1024, 256);
    gemm_bf16<true><<<512, 256, 0, stream>>>(actA, wT, g_b2, actB, 1024, 1024, 1024);
    gating_kernel<<<2048, 256, 0, stream>>>(actB, g_w3, g_b3, coeffs);

    // 3. MoE layer 0: K=576 (nkt=18), dout=1024 -> actA
    transpose_cvt<<<1152, 256, 0, stream>>>(w[0], wT, 576, 1024, 144);
    gemm_fused<true, false><<<1024, 512, 0, stream>>>(
        xc0, wT, coeffs, bb[0], actA, 576, 1024);

    // 4. MoE layers 1..4: K=1024 (nkt=32), dout=1024, ping-pong actA/actB
    unsigned short* bufs[2] = {actA, actB};
    for (int l = 1; l <= 4; ++l) {
        unsigned short* in  = bufs[(l + 1) & 1];
        unsigned short* out = bufs[l & 1];
        transpose_cvt<<<2048, 256, 0, stream>>>(w[l], wT, 1024, 1024, 256);
        gemm_fused<true, false><<<1024, 512, 0, stream>>>(
            in, wT, coeffs, bb[l], out, 1024, 1024);
    }

    // 5. MoE layer 5: K=1024, dout=512, fp32 out
    transpose_cvt<<<1024, 256, 0, stream>>>(w[5], wT, 1024, 512, 128);
    gemm_fused<false, true><<<512, 512, 0, stream>>>(
        actA, wT, coeffs, bb[5], d_out, 1024, 512);
}

// Round 17
// 761.897 us; speedup vs baseline: 1.1215x; 1.1215x over previous
//
#include <hip/hip_runtime.h>
#include <hip/hip_bf16.h>

typedef __attribute__((ext_vector_type(8))) short bf16x8;
typedef __attribute__((ext_vector_type(4))) float f32x4;

__device__ __forceinline__ float bf2f(unsigned short u) {
    union { unsigned int i; float f; } v; v.i = ((unsigned int)u) << 16; return v.f;
}
__device__ __forceinline__ unsigned short f2bf(float f) {
    union { float f; unsigned int i; } v; v.f = f;
    unsigned int x = v.i;
    return (unsigned short)((x + 0x7FFFu + ((x >> 16) & 1u)) >> 16);
}

__device__ __forceinline__ void gload_lds16(const unsigned short* g, unsigned short* l) {
    __builtin_amdgcn_global_load_lds(
        (const __attribute__((address_space(1))) unsigned int*)g,
        (__attribute__((address_space(3))) unsigned int*)l,
        16, 0, 0);
}

#define VM0  asm volatile("s_waitcnt vmcnt(0)" ::: "memory")
#define SB0  __builtin_amdgcn_sched_barrier(0)
#define BAR  __builtin_amdgcn_s_barrier()

// ---------------------------------------------------------------------------
// concat(motion, command) -> bf16 [8192, 576]
// ---------------------------------------------------------------------------
__global__ void concat_cvt(const float* __restrict__ motion,
                           const float* __restrict__ command,
                           unsigned short* __restrict__ out) {
    int id = blockIdx.x * 256 + threadIdx.x;
    int b = id / 144, q = id % 144;
    float4 v;
    if (q < 128) v = *(const float4*)(motion + (size_t)b * 512 + q * 4);
    else         v = *(const float4*)(command + (size_t)b * 64 + (q - 128) * 4);
    ushort4 o;
    o.x = f2bf(v.x); o.y = f2bf(v.y); o.z = f2bf(v.z); o.w = f2bf(v.w);
    *(ushort4*)(out + (size_t)b * 576 + q * 4) = o;
}

// ---------------------------------------------------------------------------
// batched fp32 [K,N] -> bf16 [N,K] per expert (tpe = 64x64 tiles per expert)
// ---------------------------------------------------------------------------
__global__ void transpose_cvt(const float* __restrict__ in,
                              unsigned short* __restrict__ out,
                              int K, int N, int tpe) {
    __shared__ unsigned short tile[64][72];
    int e = blockIdx.x / tpe, r = blockIdx.x % tpe;
    in  += (size_t)e * K * N;
    out += (size_t)e * N * K;
    int nbn = N / 64;
    int k0 = (r / nbn) * 64;
    int n0 = (r % nbn) * 64;
    int t = threadIdx.x;
    int tx = t & 63, ty = t >> 6;
    #pragma unroll
    for (int rr = 0; rr < 16; ++rr) {
        int kr = ty + rr * 4;
        tile[kr][tx] = f2bf(in[(size_t)(k0 + kr) * N + n0 + tx]);
    }
    __syncthreads();
    int txh = t & 31, tyh = t >> 5;
    #pragma unroll
    for (int rr = 0; rr < 8; ++rr) {
        int nr = tyh + rr * 8;
        unsigned int vlo = tile[2 * txh][nr];
        unsigned int vhi = tile[2 * txh + 1][nr];
        unsigned int* o32 = (unsigned int*)(out + (size_t)(n0 + nr) * K + k0);
        o32[txh] = vlo | (vhi << 16);
    }
}

// ---------------------------------------------------------------------------
// gating final: coeffs = softmax(g2 @ w3 + b3)
// ---------------------------------------------------------------------------
__global__ __launch_bounds__(256) void gating_kernel(
    const unsigned short* __restrict__ g2,
    const float* __restrict__ w3, const float* __restrict__ b3,
    float* __restrict__ coeffs) {
    __shared__ float w3s[8][1024];
    int t = threadIdx.x;
    for (int i = t; i < 1024; i += 256) {
        #pragma unroll
        for (int e = 0; e < 8; ++e) w3s[e][i] = w3[(size_t)i * 8 + e];
    }
    __syncthreads();
    int lane = t & 63, wv = t >> 6;
    int row = blockIdx.x * 4 + wv;
    const unsigned short* xr = g2 + (size_t)row * 1024;
    float acc[8];
    #pragma unroll
    for (int e = 0; e < 8; ++e) acc[e] = 0.f;
    for (int it = 0; it < 16; ++it) {
        float xv = bf2f(xr[lane + it * 64]);
        #pragma unroll
        for (int e = 0; e < 8; ++e) acc[e] += xv * w3s[e][lane + it * 64];
    }
    #pragma unroll
    for (int e = 0; e < 8; ++e) {
        float v = acc[e];
        #pragma unroll
        for (int off = 32; off; off >>= 1) v += __shfl_xor(v, off);
        acc[e] = v + b3[e];
    }
    float mx = acc[0];
    #pragma unroll
    for (int e = 1; e < 8; ++e) mx = fmaxf(mx, acc[e]);
    float s = 0.f;
    #pragma unroll
    for (int e = 0; e < 8; ++e) { acc[e] = __expf(acc[e] - mx); s += acc[e]; }
    float inv = 1.f / s;
    if (lane < 8) coeffs[(size_t)row * 8 + lane] = acc[lane] * inv;
}

// ---------------------------------------------------------------------------
// gating GEMM (proven): 128x128x64, global_load_lds both operands, 4 blk/CU
// ---------------------------------------------------------------------------
template<bool DO_ELU>
__global__ __launch_bounds__(256, 4)
void gemm_bf16(const unsigned short* __restrict__ A,
               const unsigned short* __restrict__ BT,
               const float* __restrict__ bias,
               unsigned short* __restrict__ Out,
               int N, int ld, int kpart) {
    __shared__ unsigned short As[128 * 64];
    __shared__ unsigned short Bs[128 * 64];
    int ntn = N >> 7;
    int nwg = gridDim.x;
    int bid = blockIdx.x;
    { int cpx = nwg >> 3; bid = (bid & 7) * cpx + (bid >> 3); }
    int tm = bid / ntn, tn = bid - tm * ntn;
    int row0 = tm << 7, col0 = tn << 7;
    int t = threadIdx.x;
    int lane = t & 63;
    int wid = t >> 6;
    int wr = wid >> 1, wc = wid & 1;
    const unsigned short* Ab = A + (size_t)(row0 + wid * 32 + (lane >> 3)) * ld + (lane & 7) * 8;
    const unsigned short* Bb = BT + (size_t)(col0 + wid * 32 + (lane >> 3)) * ld + (lane & 7) * 8;
    unsigned short* Asd = &As[wid * 32 * 64];
    unsigned short* Bsd = &Bs[wid * 32 * 64];
    f32x4 acc[4][4];
    #pragma unroll
    for (int i = 0; i < 4; ++i)
        #pragma unroll
        for (int j = 0; j < 4; ++j) acc[i][j] = (f32x4){0.f, 0.f, 0.f, 0.f};
    int nkt = kpart >> 6;
    for (int kt = 0; kt < nkt; ++kt) {
        size_t ko = (size_t)kt << 6;
        #pragma unroll
        for (int q = 0; q < 4; ++q) {
            gload_lds16(Ab + (size_t)(q * 8) * ld + ko, Asd + q * 8 * 64);
            gload_lds16(Bb + (size_t)(q * 8) * ld + ko, Bsd + q * 8 * 64);
        }
        __syncthreads();
        #pragma unroll
        for (int kk = 0; kk < 2; ++kk) {
            bf16x8 af[4], bfr[4];
            #pragma unroll
            for (int m = 0; m < 4; ++m)
                af[m] = *(const bf16x8*)(&As[(wr * 64 + m * 16 + (lane & 15)) * 64 + kk * 32 + (lane >> 4) * 8]);
            #pragma unroll
            for (int n = 0; n < 4; ++n)
                bfr[n] = *(const bf16x8*)(&Bs[(wc * 64 + n * 16 + (lane & 15)) * 64 + kk * 32 + (lane >> 4) * 8]);
            #pragma unroll
            for (int m = 0; m < 4; ++m)
                #pragma unroll
                for (int n = 0; n < 4; ++n)
                    acc[m][n] = __builtin_amdgcn_mfma_f32_16x16x32_bf16(af[m], bfr[n], acc[m][n], 0, 0, 0);
        }
        __syncthreads();
    }
    #pragma unroll
    for (int m = 0; m < 4; ++m) {
        int rbase = row0 + wr * 64 + m * 16 + ((lane >> 4) << 2);
        #pragma unroll
        for (int n = 0; n < 4; ++n) {
            int cg = col0 + wc * 64 + n * 16 + (lane & 15);
            float bv = bias[cg];
            #pragma unroll
            for (int r2 = 0; r2 < 4; ++r2) {
                float v = acc[m][n][r2] + bv;
                if (DO_ELU) v = v > 0.f ? v : (__expf(v) - 1.f);
                Out[(size_t)(rbase + r2) * N + cg] = f2bf(v);
            }
        }
    }
}

// ---------------------------------------------------------------------------
// Fused MoE GEMM (r12 base + RACE-FREE stagger): 256x256-virtual tile,
// 8 waves (wave = 128x64v), BK=32 slots, 4-slot LDS ring (128 KB), swizzled
// staging/reads, swapped-operand MFMA. Per 2-slot iteration:
//   VM0 -> BAR -> stage(s+2,s+3) -> compute (staggered order)
// Race proof: a wave staging at iter u passed iter u's BAR => ALL waves did
// => all completed iter u-1's compute (program order); iter u's stage targets
// exactly the ring slots read at iter u-1 => safe for ANY compute order.
// Stagger: half the waves compute (s,s+1), other half (s+1,s) -> opposite-
// phase waves per SIMD overlap ds_read with MFMA (T5 role-split).
// 2D XCD map (r12 proven, FETCH 94 MB).
// Epilogue: in-register expert mix -> LDS fp32 partials -> y store direct.
// ---------------------------------------------------------------------------
template<bool DO_ELU, bool OUT_F32>
__global__ __launch_bounds__(512, 1)
void gemm_fused(const unsigned short* __restrict__ A,   // [8192, K]
                const unsigned short* __restrict__ BT,  // [8*dout, K]
                const float* __restrict__ coeffs,       // [8192, 8]
                const float* __restrict__ bias,         // [8*dout]
                void* __restrict__ Out,                 // [8192, dout]
                int K, int dout) {
    __shared__ unsigned short lds[65536];           // 4 x (A 8192 + B 8192)

    // 2D concurrency-aware XCD mapping (r12 proven)
    int bid = blockIdx.x;
    int x = bid & 7;
    int i = bid >> 3;
    int within = i & 15;
    int tm = x * 4 + (within & 3);
    int tn = (i >> 4) * 4 + (within >> 2);
    int row0 = tm << 8;
    int c0 = tn << 5;
    int nkt = K >> 5;

    int t = threadIdx.x;
    int lane = t & 63, wid = t >> 6;
    int wm = wid >> 2, wn = wid & 3;                 // 2x4 waves, each 128x64
    int q = lane >> 4;
    int l15 = lane & 15;
    int grp = ((wid >> 2) ^ wid) & 1;                // opposite per SIMD-pair

    // fragment ds_read offsets (ushort units), swizzled
    int aoff[8], boff[4];
    #pragma unroll
    for (int m = 0; m < 8; ++m) {
        int row = wm * 128 + m * 16 + l15;
        aoff[m] = row * 32 + ((q ^ ((row >> 1) & 3)) << 3);
    }
    #pragma unroll
    for (int n = 0; n < 4; ++n) {
        int row = wn * 64 + n * 16 + l15;
        boff[n] = 8192 + row * 32 + ((q ^ ((row >> 1) & 3)) << 3);
    }

    // stage source (per-thread, inverse-swizzled column)
    int srow = t >> 2;
    int scol = ((t & 3) ^ ((t >> 3) & 3)) * 8;
    const unsigned short* Asrc = A + (size_t)(row0 + srow) * K + scol;
    // virtual B rows: vr -> BT row (vr>>5)*dout + c0 + (vr&31)
    int br0 = (srow >> 5) * dout + c0 + (srow & 31);            // vr = srow
    int br1 = ((srow + 128) >> 5) * dout + c0 + (srow & 31);    // vr = srow+128
    const unsigned short* Bsrc0 = BT + (size_t)br0 * K + scol;
    const unsigned short* Bsrc1 = BT + (size_t)br1 * K + scol;
    int wdst = wid * 512;                            // wave-uniform dest term

    f32x4 acc[8][4];
    #pragma unroll
    for (int m = 0; m < 8; ++m)
        #pragma unroll
        for (int n = 0; n < 4; ++n) acc[m][n] = (f32x4){0.f, 0.f, 0.f, 0.f};

    // ---- prologue: stage slots 0, 1 ----
    #pragma unroll
    for (int S = 0; S < 2; ++S) {
        gload_lds16(Asrc + S * 32,                   &lds[S * 16384 + wdst]);
        gload_lds16(Asrc + (size_t)128 * K + S * 32, &lds[S * 16384 + 4096 + wdst]);
        gload_lds16(Bsrc0 + S * 32,                  &lds[S * 16384 + 8192 + wdst]);
        gload_lds16(Bsrc1 + S * 32,                  &lds[S * 16384 + 12288 + wdst]);
    }

    auto compute_slot = [&](int sb) {
        bf16x8 bfrg[4], afr[8];
        #pragma unroll
        for (int n = 0; n < 4; ++n)
            bfrg[n] = *(const bf16x8*)(&lds[sb + boff[n]]);
        afr[0] = *(const bf16x8*)(&lds[sb + aoff[0]]);
        afr[1] = *(const bf16x8*)(&lds[sb + aoff[1]]);
        __builtin_amdgcn_s_setprio(1);
        #pragma unroll
        for (int m = 0; m < 8; ++m) {
            if (m + 2 < 8)
                afr[m + 2] = *(const bf16x8*)(&lds[sb + aoff[m + 2]]);
            #pragma unroll
            for (int n = 0; n < 4; ++n)
                acc[m][n] = __builtin_amdgcn_mfma_f32_16x16x32_bf16(bfrg[n], afr[m], acc[m][n], 0, 0, 0);
        }
        __builtin_amdgcn_s_setprio(0);
    };

    for (int s = 0; s < nkt; s += 2) {               // nkt even (18 or 32)
        int sbA = (s & 3) << 14;
        int sbB = ((s + 1) & 3) << 14;
        bool st = (s + 2) < nkt;

        VM0; SB0;                                    // own s,s+1 loads landed
        BAR;                                         // all waves' loads published;
        SB0;                                         // all iter-(u-1) reads done
        if (st) {                                    // stage s+2,s+3 (safe now)
            int rbA = ((s + 2) & 3) << 14;
            int rbB = ((s + 3) & 3) << 14;
            int koA = (s + 2) << 5;
            int koB = (s + 3) << 5;
            gload_lds16(Asrc + koA,                   &lds[rbA + wdst]);
            gload_lds16(Asrc + (size_t)128 * K + koA, &lds[rbA + 4096 + wdst]);
            gload_lds16(Bsrc0 + koA,                  &lds[rbA + 8192 + wdst]);
            gload_lds16(Bsrc1 + koA,                  &lds[rbA + 12288 + wdst]);
            gload_lds16(Asrc + koB,                   &lds[rbB + wdst]);
            gload_lds16(Asrc + (size_t)128 * K + koB, &lds[rbB + 4096 + wdst]);
            gload_lds16(Bsrc0 + koB,                  &lds[rbB + 8192 + wdst]);
            gload_lds16(Bsrc1 + koB,                  &lds[rbB + 12288 + wdst]);
        }
        SB0;

        // phase-staggered slot order: opposite-phase waves per SIMD
        if (grp == 0) {
            compute_slot(sbA);
            compute_slot(sbB);
        } else {
            compute_slot(sbB);
            compute_slot(sbA);
        }
        SB0;
    }

    // ======== epilogue phase 1: per-wave expert mix -> LDS fp32 partials ===
    float* plds = (float*)lds;                       // 8 regions x [128][32] f32
    __syncthreads();                                 // ring fully consumed
    {
        int e0 = 2 * wn, e1 = e0 + 1;
        f32x4 b0h[2], b1h[2];
        #pragma unroll
        for (int h = 0; h < 2; ++h) {
            float4 u0 = *(const float4*)(bias + e0 * dout + c0 + h * 16 + q * 4);
            float4 u1 = *(const float4*)(bias + e1 * dout + c0 + h * 16 + q * 4);
            b0h[h] = (f32x4){u0.x, u0.y, u0.z, u0.w};
            b1h[h] = (f32x4){u1.x, u1.y, u1.z, u1.w};
        }
        float* preg = plds + (wid << 12);
        #pragma unroll
        for (int m = 0; m < 8; ++m) {
            int grow = row0 + wm * 128 + m * 16 + l15;
            float c8 = coeffs[(size_t)grow * 8 + e0];
            float c9 = coeffs[(size_t)grow * 8 + e1];
            #pragma unroll
            for (int h = 0; h < 2; ++h) {
                f32x4 z0 = acc[m][h];
                f32x4 z1 = acc[m][h + 2];
                f32x4 p;
                #pragma unroll
                for (int r = 0; r < 4; ++r)
                    p[r] = c8 * (z0[r] + b0h[h][r]) + c9 * (z1[r] + b1h[h][r]);
                int row = m * 16 + l15;
                int slot = (h * 4 + q) ^ (row & 7);
                *(f32x4*)(preg + row * 32 + (slot << 2)) = p;
            }
        }
    }
    __syncthreads();

    // ======== epilogue phase 2: sum 4 wn-partials, act, store ==============
    {
        int r2 = t >> 1;                             // tile row 0..255
        int ch = t & 1;                              // col half (16 cols)
        int wmr = r2 >> 7;
        int rr = r2 & 127;
        int sw = rr & 7;
        size_t obase = (size_t)(row0 + r2) * dout + c0 + ch * 16;
        #pragma unroll
        for (int sl = 0; sl < 4; ++sl) {
            int L = ch * 4 + sl;
            int phys = L ^ sw;
            f32x4 sum = (f32x4){0.f, 0.f, 0.f, 0.f};
            #pragma unroll
            for (int w2 = 0; w2 < 4; ++w2) {
                const f32x4 v = *(const f32x4*)(plds + (((wmr << 2) + w2) << 12) + rr * 32 + (phys << 2));
                sum[0] += v[0]; sum[1] += v[1]; sum[2] += v[2]; sum[3] += v[3];
            }
            if (DO_ELU) {
                #pragma unroll
                for (int r = 0; r < 4; ++r)
                    sum[r] = sum[r] > 0.f ? sum[r] : (__expf(sum[r]) - 1.f);
            }
            if (OUT_F32) {
                float4 o = {sum[0], sum[1], sum[2], sum[3]};
                *(float4*)((float*)Out + obase + sl * 4) = o;
            } else {
                ushort4 o;
                o.x = f2bf(sum[0]); o.y = f2bf(sum[1]);
                o.z = f2bf(sum[2]); o.w = f2bf(sum[3]);
                *(ushort4*)((unsigned short*)Out + obase + sl * 4) = o;
            }
        }
    }
}

// ---------------------------------------------------------------------------
extern "C" void kernel_launch(void* const* d_in, const int* in_sizes, int n_in,
                              void* d_out, int out_size, void* d_ws, size_t ws_size,
                              hipStream_t stream) {
    const float* motion  = (const float*)d_in[0];
    const float* command = (const float*)d_in[1];
    const float* g_w1 = (const float*)d_in[2];
    const float* g_b1 = (const float*)d_in[3];
    const float* g_w2 = (const float*)d_in[4];
    const float* g_b2 = (const float*)d_in[5];
    const float* g_w3 = (const float*)d_in[6];
    const float* g_b3 = (const float*)d_in[7];
    const float* w[6]  = {(const float*)d_in[8],  (const float*)d_in[10],
                          (const float*)d_in[12], (const float*)d_in[14],
                          (const float*)d_in[16], (const float*)d_in[18]};
    const float* bb[6] = {(const float*)d_in[9],  (const float*)d_in[11],
                          (const float*)d_in[13], (const float*)d_in[15],
                          (const float*)d_in[17], (const float*)d_in[19]};

    char* ws = (char*)d_ws;
    unsigned short* xc0  = (unsigned short*)ws;                 //  9,437,184
    unsigned short* actA = (unsigned short*)(ws + 9437184);     // 16,777,216
    unsigned short* actB = (unsigned short*)(ws + 26214400);    // 16,777,216
    float* coeffs        = (float*)(ws + 42991616);             //    262,144
    unsigned short* wT   = (unsigned short*)(ws + 43253760);    // 16,777,216

    // 1. concat + convert input
    concat_cvt<<<4608, 256, 0, stream>>>(motion, command, xc0);

    // 2. gating network
    transpose_cvt<<<144, 256, 0, stream>>>(g_w1, wT, 576, 1024, 144);
    gemm_bf16<true><<<512, 256, 0, stream>>>(xc0, wT, g_b1, actA, 1024, 576, 576);
    transpose_cvt<<<256, 256, 0, stream>>>(g_w2, wT, 1024, 1024, 256);
    gemm_bf16<true><<<512, 256, 0, stream>>>(actA, wT, g_b2, actB, 1024, 1024, 1024);
    gating_kernel<<<2048, 256, 0, stream>>>(actB, g_w3, g_b3, coeffs);

    // 3. MoE layer 0: K=576 (nkt=18), dout=1024 -> actA
    transpose_cvt<<<1152, 256, 0, stream>>>(w[0], wT, 576, 1024, 144);
    gemm_fused<true, false><<<1024, 512, 0, stream>>>(
        xc0, wT, coeffs, bb[0], actA, 576, 1024);

    // 4. MoE layers 1..4: K=1024 (nkt=32), dout=1024, ping-pong actA/actB
    unsigned short* bufs[2] = {actA, actB};
    for (int l = 1; l <= 4; ++l) {
        unsigned short* in  = bufs[(l + 1) & 1];
        unsigned short* out = bufs[l & 1];
        transpose_cvt<<<2048, 256, 0, stream>>>(w[l], wT, 1024, 1024, 256);
        gemm_fused<true, false><<<1024, 512, 0, stream>>>(
            in, wT, coeffs, bb[l], out, 1024, 1024);
    }

    // 5. MoE layer 5: K=1024, dout=512, fp32 out
    transpose_cvt<<<1024, 256, 0, stream>>>(w[5], wT, 1024, 512, 128);
    gemm_fused<false, true><<<512, 512, 0, stream>>>(
        actA, wT, coeffs, bb[5], d_out, 1024, 512);
}

// Round 18
// 708.728 us; speedup vs baseline: 1.2056x; 1.0750x over previous
//
#include <hip/hip_runtime.h>
#include <hip/hip_bf16.h>

typedef __attribute__((ext_vector_type(8))) short bf16x8;
typedef __attribute__((ext_vector_type(4))) float f32x4;

__device__ __forceinline__ float bf2f(unsigned short u) {
    union { unsigned int i; float f; } v; v.i = ((unsigned int)u) << 16; return v.f;
}
__device__ __forceinline__ unsigned short f2bf(float f) {
    union { float f; unsigned int i; } v; v.f = f;
    unsigned int x = v.i;
    return (unsigned short)((x + 0x7FFFu + ((x >> 16) & 1u)) >> 16);
}

__device__ __forceinline__ void gload_lds16(const unsigned short* g, unsigned short* l) {
    __builtin_amdgcn_global_load_lds(
        (const __attribute__((address_space(1))) unsigned int*)g,
        (__attribute__((address_space(3))) unsigned int*)l,
        16, 0, 0);
}

#define VM8  asm volatile("s_waitcnt vmcnt(8)" ::: "memory")
#define VM0  asm volatile("s_waitcnt vmcnt(0)" ::: "memory")
#define SB0  __builtin_amdgcn_sched_barrier(0)
#define BAR  __builtin_amdgcn_s_barrier()

// ---------------------------------------------------------------------------
// concat(motion, command) -> bf16 [8192, 576]
// ---------------------------------------------------------------------------
__global__ void concat_cvt(const float* __restrict__ motion,
                           const float* __restrict__ command,
                           unsigned short* __restrict__ out) {
    int id = blockIdx.x * 256 + threadIdx.x;
    int b = id / 144, q = id % 144;
    float4 v;
    if (q < 128) v = *(const float4*)(motion + (size_t)b * 512 + q * 4);
    else         v = *(const float4*)(command + (size_t)b * 64 + (q - 128) * 4);
    ushort4 o;
    o.x = f2bf(v.x); o.y = f2bf(v.y); o.z = f2bf(v.z); o.w = f2bf(v.w);
    *(ushort4*)(out + (size_t)b * 576 + q * 4) = o;
}

// ---------------------------------------------------------------------------
// batched fp32 [K,N] -> bf16 [N,K] per expert (tpe = 64x64 tiles per expert)
// ---------------------------------------------------------------------------
__global__ void transpose_cvt(const float* __restrict__ in,
                              unsigned short* __restrict__ out,
                              int K, int N, int tpe) {
    __shared__ unsigned short tile[64][72];
    int e = blockIdx.x / tpe, r = blockIdx.x % tpe;
    in  += (size_t)e * K * N;
    out += (size_t)e * N * K;
    int nbn = N / 64;
    int k0 = (r / nbn) * 64;
    int n0 = (r % nbn) * 64;
    int t = threadIdx.x;
    int tx = t & 63, ty = t >> 6;
    #pragma unroll
    for (int rr = 0; rr < 16; ++rr) {
        int kr = ty + rr * 4;
        tile[kr][tx] = f2bf(in[(size_t)(k0 + kr) * N + n0 + tx]);
    }
    __syncthreads();
    int txh = t & 31, tyh = t >> 5;
    #pragma unroll
    for (int rr = 0; rr < 8; ++rr) {
        int nr = tyh + rr * 8;
        unsigned int vlo = tile[2 * txh][nr];
        unsigned int vhi = tile[2 * txh + 1][nr];
        unsigned int* o32 = (unsigned int*)(out + (size_t)(n0 + nr) * K + k0);
        o32[txh] = vlo | (vhi << 16);
    }
}

// ---------------------------------------------------------------------------
// gating final: coeffs = softmax(g2 @ w3 + b3)
// ---------------------------------------------------------------------------
__global__ __launch_bounds__(256) void gating_kernel(
    const unsigned short* __restrict__ g2,
    const float* __restrict__ w3, const float* __restrict__ b3,
    float* __restrict__ coeffs) {
    __shared__ float w3s[8][1024];
    int t = threadIdx.x;
    for (int i = t; i < 1024; i += 256) {
        #pragma unroll
        for (int e = 0; e < 8; ++e) w3s[e][i] = w3[(size_t)i * 8 + e];
    }
    __syncthreads();
    int lane = t & 63, wv = t >> 6;
    int row = blockIdx.x * 4 + wv;
    const unsigned short* xr = g2 + (size_t)row * 1024;
    float acc[8];
    #pragma unroll
    for (int e = 0; e < 8; ++e) acc[e] = 0.f;
    for (int it = 0; it < 16; ++it) {
        float xv = bf2f(xr[lane + it * 64]);
        #pragma unroll
        for (int e = 0; e < 8; ++e) acc[e] += xv * w3s[e][lane + it * 64];
    }
    #pragma unroll
    for (int e = 0; e < 8; ++e) {
        float v = acc[e];
        #pragma unroll
        for (int off = 32; off; off >>= 1) v += __shfl_xor(v, off);
        acc[e] = v + b3[e];
    }
    float mx = acc[0];
    #pragma unroll
    for (int e = 1; e < 8; ++e) mx = fmaxf(mx, acc[e]);
    float s = 0.f;
    #pragma unroll
    for (int e = 0; e < 8; ++e) { acc[e] = __expf(acc[e] - mx); s += acc[e]; }
    float inv = 1.f / s;
    if (lane < 8) coeffs[(size_t)row * 8 + lane] = acc[lane] * inv;
}

// ---------------------------------------------------------------------------
// gating GEMM (proven): 128x128x64, global_load_lds both operands, 4 blk/CU
// ---------------------------------------------------------------------------
template<bool DO_ELU>
__global__ __launch_bounds__(256, 4)
void gemm_bf16(const unsigned short* __restrict__ A,
               const unsigned short* __restrict__ BT,
               const float* __restrict__ bias,
               unsigned short* __restrict__ Out,
               int N, int ld, int kpart) {
    __shared__ unsigned short As[128 * 64];
    __shared__ unsigned short Bs[128 * 64];
    int ntn = N >> 7;
    int nwg = gridDim.x;
    int bid = blockIdx.x;
    { int cpx = nwg >> 3; bid = (bid & 7) * cpx + (bid >> 3); }
    int tm = bid / ntn, tn = bid - tm * ntn;
    int row0 = tm << 7, col0 = tn << 7;
    int t = threadIdx.x;
    int lane = t & 63;
    int wid = t >> 6;
    int wr = wid >> 1, wc = wid & 1;
    const unsigned short* Ab = A + (size_t)(row0 + wid * 32 + (lane >> 3)) * ld + (lane & 7) * 8;
    const unsigned short* Bb = BT + (size_t)(col0 + wid * 32 + (lane >> 3)) * ld + (lane & 7) * 8;
    unsigned short* Asd = &As[wid * 32 * 64];
    unsigned short* Bsd = &Bs[wid * 32 * 64];
    f32x4 acc[4][4];
    #pragma unroll
    for (int i = 0; i < 4; ++i)
        #pragma unroll
        for (int j = 0; j < 4; ++j) acc[i][j] = (f32x4){0.f, 0.f, 0.f, 0.f};
    int nkt = kpart >> 6;
    for (int kt = 0; kt < nkt; ++kt) {
        size_t ko = (size_t)kt << 6;
        #pragma unroll
        for (int q = 0; q < 4; ++q) {
            gload_lds16(Ab + (size_t)(q * 8) * ld + ko, Asd + q * 8 * 64);
            gload_lds16(Bb + (size_t)(q * 8) * ld + ko, Bsd + q * 8 * 64);
        }
        __syncthreads();
        #pragma unroll
        for (int kk = 0; kk < 2; ++kk) {
            bf16x8 af[4], bfr[4];
            #pragma unroll
            for (int m = 0; m < 4; ++m)
                af[m] = *(const bf16x8*)(&As[(wr * 64 + m * 16 + (lane & 15)) * 64 + kk * 32 + (lane >> 4) * 8]);
            #pragma unroll
            for (int n = 0; n < 4; ++n)
                bfr[n] = *(const bf16x8*)(&Bs[(wc * 64 + n * 16 + (lane & 15)) * 64 + kk * 32 + (lane >> 4) * 8]);
            #pragma unroll
            for (int m = 0; m < 4; ++m)
                #pragma unroll
                for (int n = 0; n < 4; ++n)
                    acc[m][n] = __builtin_amdgcn_mfma_f32_16x16x32_bf16(af[m], bfr[n], acc[m][n], 0, 0, 0);
        }
        __syncthreads();
    }
    #pragma unroll
    for (int m = 0; m < 4; ++m) {
        int rbase = row0 + wr * 64 + m * 16 + ((lane >> 4) << 2);
        #pragma unroll
        for (int n = 0; n < 4; ++n) {
            int cg = col0 + wc * 64 + n * 16 + (lane & 15);
            float bv = bias[cg];
            #pragma unroll
            for (int r2 = 0; r2 < 4; ++r2) {
                float v = acc[m][n][r2] + bv;
                if (DO_ELU) v = v > 0.f ? v : (__expf(v) - 1.f);
                Out[(size_t)(rbase + r2) * N + cg] = f2bf(v);
            }
        }
    }
}

// ---------------------------------------------------------------------------
// Fused MoE GEMM (r14, proven best: 132 us/mid-layer): 256x256-virtual tile,
// 8 waves (wave = 128x64v), BK=32 slots, 4-slot LDS ring (128 KB), swizzled
// staging/reads, swapped-operand MFMA. Per iteration (2 slots): stage
// s+2,s+3 (8 loads, targets bufs read at iter u-2: race-free) -> VM8
// (counted: drains s,s+1, keeps s+2,s+3 in flight) -> barrier -> per slot
// {B0-3,A0,A1 reads; then alternate read A(m+2) / 4-MFMA cluster}.
// 2D XCD map (r12 proven, FETCH 94 MB).
// Epilogue: in-register expert mix -> LDS fp32 partials -> y store direct.
// ---------------------------------------------------------------------------
template<bool DO_ELU, bool OUT_F32>
__global__ __launch_bounds__(512, 1)
void gemm_fused(const unsigned short* __restrict__ A,   // [8192, K]
                const unsigned short* __restrict__ BT,  // [8*dout, K]
                const float* __restrict__ coeffs,       // [8192, 8]
                const float* __restrict__ bias,         // [8*dout]
                void* __restrict__ Out,                 // [8192, dout]
                int K, int dout) {
    __shared__ unsigned short lds[65536];           // 4 x (A 8192 + B 8192)

    // 2D concurrency-aware XCD mapping (r12 proven)
    int bid = blockIdx.x;
    int x = bid & 7;
    int i = bid >> 3;
    int within = i & 15;
    int tm = x * 4 + (within & 3);
    int tn = (i >> 4) * 4 + (within >> 2);
    int row0 = tm << 8;
    int c0 = tn << 5;
    int nkt = K >> 5;

    int t = threadIdx.x;
    int lane = t & 63, wid = t >> 6;
    int wm = wid >> 2, wn = wid & 3;                 // 2x4 waves, each 128x64
    int q = lane >> 4;
    int l15 = lane & 15;

    // fragment ds_read offsets (ushort units), swizzled
    int aoff[8], boff[4];
    #pragma unroll
    for (int m = 0; m < 8; ++m) {
        int row = wm * 128 + m * 16 + l15;
        aoff[m] = row * 32 + ((q ^ ((row >> 1) & 3)) << 3);
    }
    #pragma unroll
    for (int n = 0; n < 4; ++n) {
        int row = wn * 64 + n * 16 + l15;
        boff[n] = 8192 + row * 32 + ((q ^ ((row >> 1) & 3)) << 3);
    }

    // stage source (per-thread, inverse-swizzled column)
    int srow = t >> 2;
    int scol = ((t & 3) ^ ((t >> 3) & 3)) * 8;
    const unsigned short* Asrc = A + (size_t)(row0 + srow) * K + scol;
    // virtual B rows: vr -> BT row (vr>>5)*dout + c0 + (vr&31)
    int br0 = (srow >> 5) * dout + c0 + (srow & 31);            // vr = srow
    int br1 = ((srow + 128) >> 5) * dout + c0 + (srow & 31);    // vr = srow+128
    const unsigned short* Bsrc0 = BT + (size_t)br0 * K + scol;
    const unsigned short* Bsrc1 = BT + (size_t)br1 * K + scol;
    int wdst = wid * 512;                            // wave-uniform dest term

    f32x4 acc[8][4];
    #pragma unroll
    for (int m = 0; m < 8; ++m)
        #pragma unroll
        for (int n = 0; n < 4; ++n) acc[m][n] = (f32x4){0.f, 0.f, 0.f, 0.f};

    // ---- prologue: stage slots 0, 1 ----
    #pragma unroll
    for (int S = 0; S < 2; ++S) {
        gload_lds16(Asrc + S * 32,                   &lds[S * 16384 + wdst]);
        gload_lds16(Asrc + (size_t)128 * K + S * 32, &lds[S * 16384 + 4096 + wdst]);
        gload_lds16(Bsrc0 + S * 32,                  &lds[S * 16384 + 8192 + wdst]);
        gload_lds16(Bsrc1 + S * 32,                  &lds[S * 16384 + 12288 + wdst]);
    }

    for (int s = 0; s < nkt; s += 2) {               // nkt even (18 or 32)
        int sbA = (s & 3) << 14;
        int sbB = ((s + 1) & 3) << 14;
        bool st = (s + 2) < nkt;

        // stage s+2, s+3 FIRST (targets bufs read at s-2: safe; issues early)
        if (st) {
            int rbA = ((s + 2) & 3) << 14;
            int rbB = ((s + 3) & 3) << 14;
            int koA = (s + 2) << 5;
            int koB = (s + 3) << 5;
            gload_lds16(Asrc + koA,                   &lds[rbA + wdst]);
            gload_lds16(Asrc + (size_t)128 * K + koA, &lds[rbA + 4096 + wdst]);
            gload_lds16(Bsrc0 + koA,                  &lds[rbA + 8192 + wdst]);
            gload_lds16(Bsrc1 + koA,                  &lds[rbA + 12288 + wdst]);
            gload_lds16(Asrc + koB,                   &lds[rbB + wdst]);
            gload_lds16(Asrc + (size_t)128 * K + koB, &lds[rbB + 4096 + wdst]);
            gload_lds16(Bsrc0 + koB,                  &lds[rbB + 8192 + wdst]);
            gload_lds16(Bsrc1 + koB,                  &lds[rbB + 12288 + wdst]);
        }
        SB0;
        if (st) { VM8; } else { VM0; }               // drain s,s+1; keep s+2,s+3
        SB0;
        BAR;                                         // all waves' s,s+1 published
        SB0;

        // ---- slot s: interleaved reads/MFMA ----
        {
            bf16x8 bfrg[4], afr[8];
            #pragma unroll
            for (int n = 0; n < 4; ++n)
                bfrg[n] = *(const bf16x8*)(&lds[sbA + boff[n]]);
            afr[0] = *(const bf16x8*)(&lds[sbA + aoff[0]]);
            afr[1] = *(const bf16x8*)(&lds[sbA + aoff[1]]);
            __builtin_amdgcn_s_setprio(1);
            #pragma unroll
            for (int m = 0; m < 8; ++m) {
                if (m + 2 < 8)
                    afr[m + 2] = *(const bf16x8*)(&lds[sbA + aoff[m + 2]]);
                #pragma unroll
                for (int n = 0; n < 4; ++n)
                    acc[m][n] = __builtin_amdgcn_mfma_f32_16x16x32_bf16(bfrg[n], afr[m], acc[m][n], 0, 0, 0);
            }
            __builtin_amdgcn_s_setprio(0);
        }
        // ---- slot s+1: interleaved reads/MFMA ----
        {
            bf16x8 bfrg[4], afr[8];
            #pragma unroll
            for (int n = 0; n < 4; ++n)
                bfrg[n] = *(const bf16x8*)(&lds[sbB + boff[n]]);
            afr[0] = *(const bf16x8*)(&lds[sbB + aoff[0]]);
            afr[1] = *(const bf16x8*)(&lds[sbB + aoff[1]]);
            __builtin_amdgcn_s_setprio(1);
            #pragma unroll
            for (int m = 0; m < 8; ++m) {
                if (m + 2 < 8)
                    afr[m + 2] = *(const bf16x8*)(&lds[sbB + aoff[m + 2]]);
                #pragma unroll
                for (int n = 0; n < 4; ++n)
                    acc[m][n] = __builtin_amdgcn_mfma_f32_16x16x32_bf16(bfrg[n], afr[m], acc[m][n], 0, 0, 0);
            }
            __builtin_amdgcn_s_setprio(0);
        }
        SB0;
    }

    // ======== epilogue phase 1: per-wave expert mix -> LDS fp32 partials ===
    float* plds = (float*)lds;                       // 8 regions x [128][32] f32
    __syncthreads();                                 // ring fully consumed
    {
        int e0 = 2 * wn, e1 = e0 + 1;
        f32x4 b0h[2], b1h[2];
        #pragma unroll
        for (int h = 0; h < 2; ++h) {
            float4 u0 = *(const float4*)(bias + e0 * dout + c0 + h * 16 + q * 4);
            float4 u1 = *(const float4*)(bias + e1 * dout + c0 + h * 16 + q * 4);
            b0h[h] = (f32x4){u0.x, u0.y, u0.z, u0.w};
            b1h[h] = (f32x4){u1.x, u1.y, u1.z, u1.w};
        }
        float* preg = plds + (wid << 12);
        #pragma unroll
        for (int m = 0; m < 8; ++m) {
            int grow = row0 + wm * 128 + m * 16 + l15;
            float c8 = coeffs[(size_t)grow * 8 + e0];
            float c9 = coeffs[(size_t)grow * 8 + e1];
            #pragma unroll
            for (int h = 0; h < 2; ++h) {
                f32x4 z0 = acc[m][h];
                f32x4 z1 = acc[m][h + 2];
                f32x4 p;
                #pragma unroll
                for (int r = 0; r < 4; ++r)
                    p[r] = c8 * (z0[r] + b0h[h][r]) + c9 * (z1[r] + b1h[h][r]);
                int row = m * 16 + l15;
                int slot = (h * 4 + q) ^ (row & 7);
                *(f32x4*)(preg + row * 32 + (slot << 2)) = p;
            }
        }
    }
    __syncthreads();

    // ======== epilogue phase 2: sum 4 wn-partials, act, store ==============
    {
        int r2 = t >> 1;                             // tile row 0..255
        int ch = t & 1;                              // col half (16 cols)
        int wmr = r2 >> 7;
        int rr = r2 & 127;
        int sw = rr & 7;
        size_t obase = (size_t)(row0 + r2) * dout + c0 + ch * 16;
        #pragma unroll
        for (int sl = 0; sl < 4; ++sl) {
            int L = ch * 4 + sl;
            int phys = L ^ sw;
            f32x4 sum = (f32x4){0.f, 0.f, 0.f, 0.f};
            #pragma unroll
            for (int w2 = 0; w2 < 4; ++w2) {
                const f32x4 v = *(const f32x4*)(plds + (((wmr << 2) + w2) << 12) + rr * 32 + (phys << 2));
                sum[0] += v[0]; sum[1] += v[1]; sum[2] += v[2]; sum[3] += v[3];
            }
            if (DO_ELU) {
                #pragma unroll
                for (int r = 0; r < 4; ++r)
                    sum[r] = sum[r] > 0.f ? sum[r] : (__expf(sum[r]) - 1.f);
            }
            if (OUT_F32) {
                float4 o = {sum[0], sum[1], sum[2], sum[3]};
                *(float4*)((float*)Out + obase + sl * 4) = o;
            } else {
                ushort4 o;
                o.x = f2bf(sum[0]); o.y = f2bf(sum[1]);
                o.z = f2bf(sum[2]); o.w = f2bf(sum[3]);
                *(ushort4*)((unsigned short*)Out + obase + sl * 4) = o;
            }
        }
    }
}

// ---------------------------------------------------------------------------
extern "C" void kernel_launch(void* const* d_in, const int* in_sizes, int n_in,
                              void* d_out, int out_size, void* d_ws, size_t ws_size,
                              hipStream_t stream) {
    const float* motion  = (const float*)d_in[0];
    const float* command = (const float*)d_in[1];
    const float* g_w1 = (const float*)d_in[2];
    const float* g_b1 = (const float*)d_in[3];
    const float* g_w2 = (const float*)d_in[4];
    const float* g_b2 = (const float*)d_in[5];
    const float* g_w3 = (const float*)d_in[6];
    const float* g_b3 = (const float*)d_in[7];
    const float* w[6]  = {(const float*)d_in[8],  (const float*)d_in[10],
                          (const float*)d_in[12], (const float*)d_in[14],
                          (const float*)d_in[16], (const float*)d_in[18]};
    const float* bb[6] = {(const float*)d_in[9],  (const float*)d_in[11],
                          (const float*)d_in[13], (const float*)d_in[15],
                          (const float*)d_in[17], (const float*)d_in[19]};

    char* ws = (char*)d_ws;
    unsigned short* xc0  = (unsigned short*)ws;                 //  9,437,184
    unsigned short* actA = (unsigned short*)(ws + 9437184);     // 16,777,216
    unsigned short* actB = (unsigned short*)(ws + 26214400);    // 16,777,216
    float* coeffs        = (float*)(ws + 42991616);             //    262,144
    unsigned short* wT   = (unsigned short*)(ws + 43253760);    // 16,777,216

    // 1. concat + convert input
    concat_cvt<<<4608, 256, 0, stream>>>(motion, command, xc0);

    // 2. gating network
    transpose_cvt<<<144, 256, 0, stream>>>(g_w1, wT, 576, 1024, 144);
    gemm_bf16<true><<<512, 256, 0, stream>>>(xc0, wT, g_b1, actA, 1024, 576, 576);
    transpose_cvt<<<256, 256, 0, stream>>>(g_w2, wT, 1024, 1024, 256);
    gemm_bf16<true><<<512, 256, 0, stream>>>(actA, wT, g_b2, actB, 1024, 1024, 1024);
    gating_kernel<<<2048, 256, 0, stream>>>(actB, g_w3, g_b3, coeffs);

    // 3. MoE layer 0: K=576 (nkt=18), dout=1024 -> actA
    transpose_cvt<<<1152, 256, 0, stream>>>(w[0], wT, 576, 1024, 144);
    gemm_fused<true, false><<<1024, 512, 0, stream>>>(
        xc0, wT, coeffs, bb[0], actA, 576, 1024);

    // 4. MoE layers 1..4: K=1024 (nkt=32), dout=1024, ping-pong actA/actB
    unsigned short* bufs[2] = {actA, actB};
    for (int l = 1; l <= 4; ++l) {
        unsigned short* in  = bufs[(l + 1) & 1];
        unsigned short* out = bufs[l & 1];
        transpose_cvt<<<2048, 256, 0, stream>>>(w[l], wT, 1024, 1024, 256);
        gemm_fused<true, false><<<1024, 512, 0, stream>>>(
            in, wT, coeffs, bb[l], out, 1024, 1024);
    }

    // 5. MoE layer 5: K=1024, dout=512, fp32 out
    transpose_cvt<<<1024, 256, 0, stream>>>(w[5], wT, 1024, 512, 128);
    gemm_fused<false, true><<<512, 512, 0, stream>>>(
        actA, wT, coeffs, bb[5], d_out, 1024, 512);
}

// Round 19
// 702.004 us; speedup vs baseline: 1.2171x; 1.0096x over previous
//
#include <hip/hip_runtime.h>
#include <hip/hip_bf16.h>

typedef __attribute__((ext_vector_type(8))) short bf16x8;
typedef __attribute__((ext_vector_type(4))) float f32x4;

__device__ __forceinline__ float bf2f(unsigned short u) {
    union { unsigned int i; float f; } v; v.i = ((unsigned int)u) << 16; return v.f;
}
__device__ __forceinline__ unsigned short f2bf(float f) {
    union { float f; unsigned int i; } v; v.f = f;
    unsigned int x = v.i;
    return (unsigned short)((x + 0x7FFFu + ((x >> 16) & 1u)) >> 16);
}

__device__ __forceinline__ void gload_lds16(const unsigned short* g, unsigned short* l) {
    __builtin_amdgcn_global_load_lds(
        (const __attribute__((address_space(1))) unsigned int*)g,
        (__attribute__((address_space(3))) unsigned int*)l,
        16, 0, 0);
}

#define VM8  asm volatile("s_waitcnt vmcnt(8)" ::: "memory")
#define VM0  asm volatile("s_waitcnt vmcnt(0)" ::: "memory")
#define SB0  __builtin_amdgcn_sched_barrier(0)
#define BAR  __builtin_amdgcn_s_barrier()
#define SGB_DS(n)   __builtin_amdgcn_sched_group_barrier(0x100, (n), 0)
#define SGB_MFMA(n) __builtin_amdgcn_sched_group_barrier(0x008, (n), 0)

// ---------------------------------------------------------------------------
// concat(motion, command) -> bf16 [8192, 576]
// ---------------------------------------------------------------------------
__global__ void concat_cvt(const float* __restrict__ motion,
                           const float* __restrict__ command,
                           unsigned short* __restrict__ out) {
    int id = blockIdx.x * 256 + threadIdx.x;
    int b = id / 144, q = id % 144;
    float4 v;
    if (q < 128) v = *(const float4*)(motion + (size_t)b * 512 + q * 4);
    else         v = *(const float4*)(command + (size_t)b * 64 + (q - 128) * 4);
    ushort4 o;
    o.x = f2bf(v.x); o.y = f2bf(v.y); o.z = f2bf(v.z); o.w = f2bf(v.w);
    *(ushort4*)(out + (size_t)b * 576 + q * 4) = o;
}

// ---------------------------------------------------------------------------
// batched fp32 [K,N] -> bf16 [N,K] per expert (tpe = 64x64 tiles per expert)
// ---------------------------------------------------------------------------
__global__ void transpose_cvt(const float* __restrict__ in,
                              unsigned short* __restrict__ out,
                              int K, int N, int tpe) {
    __shared__ unsigned short tile[64][72];
    int e = blockIdx.x / tpe, r = blockIdx.x % tpe;
    in  += (size_t)e * K * N;
    out += (size_t)e * N * K;
    int nbn = N / 64;
    int k0 = (r / nbn) * 64;
    int n0 = (r % nbn) * 64;
    int t = threadIdx.x;
    int tx = t & 63, ty = t >> 6;
    #pragma unroll
    for (int rr = 0; rr < 16; ++rr) {
        int kr = ty + rr * 4;
        tile[kr][tx] = f2bf(in[(size_t)(k0 + kr) * N + n0 + tx]);
    }
    __syncthreads();
    int txh = t & 31, tyh = t >> 5;
    #pragma unroll
    for (int rr = 0; rr < 8; ++rr) {
        int nr = tyh + rr * 8;
        unsigned int vlo = tile[2 * txh][nr];
        unsigned int vhi = tile[2 * txh + 1][nr];
        unsigned int* o32 = (unsigned int*)(out + (size_t)(n0 + nr) * K + k0);
        o32[txh] = vlo | (vhi << 16);
    }
}

// ---------------------------------------------------------------------------
// gating final: coeffs = softmax(g2 @ w3 + b3)
// ---------------------------------------------------------------------------
__global__ __launch_bounds__(256) void gating_kernel(
    const unsigned short* __restrict__ g2,
    const float* __restrict__ w3, const float* __restrict__ b3,
    float* __restrict__ coeffs) {
    __shared__ float w3s[8][1024];
    int t = threadIdx.x;
    for (int i = t; i < 1024; i += 256) {
        #pragma unroll
        for (int e = 0; e < 8; ++e) w3s[e][i] = w3[(size_t)i * 8 + e];
    }
    __syncthreads();
    int lane = t & 63, wv = t >> 6;
    int row = blockIdx.x * 4 + wv;
    const unsigned short* xr = g2 + (size_t)row * 1024;
    float acc[8];
    #pragma unroll
    for (int e = 0; e < 8; ++e) acc[e] = 0.f;
    for (int it = 0; it < 16; ++it) {
        float xv = bf2f(xr[lane + it * 64]);
        #pragma unroll
        for (int e = 0; e < 8; ++e) acc[e] += xv * w3s[e][lane + it * 64];
    }
    #pragma unroll
    for (int e = 0; e < 8; ++e) {
        float v = acc[e];
        #pragma unroll
        for (int off = 32; off; off >>= 1) v += __shfl_xor(v, off);
        acc[e] = v + b3[e];
    }
    float mx = acc[0];
    #pragma unroll
    for (int e = 1; e < 8; ++e) mx = fmaxf(mx, acc[e]);
    float s = 0.f;
    #pragma unroll
    for (int e = 0; e < 8; ++e) { acc[e] = __expf(acc[e] - mx); s += acc[e]; }
    float inv = 1.f / s;
    if (lane < 8) coeffs[(size_t)row * 8 + lane] = acc[lane] * inv;
}

// ---------------------------------------------------------------------------
// gating GEMM (proven): 128x128x64, global_load_lds both operands, 4 blk/CU
// ---------------------------------------------------------------------------
template<bool DO_ELU>
__global__ __launch_bounds__(256, 4)
void gemm_bf16(const unsigned short* __restrict__ A,
               const unsigned short* __restrict__ BT,
               const float* __restrict__ bias,
               unsigned short* __restrict__ Out,
               int N, int ld, int kpart) {
    __shared__ unsigned short As[128 * 64];
    __shared__ unsigned short Bs[128 * 64];
    int ntn = N >> 7;
    int nwg = gridDim.x;
    int bid = blockIdx.x;
    { int cpx = nwg >> 3; bid = (bid & 7) * cpx + (bid >> 3); }
    int tm = bid / ntn, tn = bid - tm * ntn;
    int row0 = tm << 7, col0 = tn << 7;
    int t = threadIdx.x;
    int lane = t & 63;
    int wid = t >> 6;
    int wr = wid >> 1, wc = wid & 1;
    const unsigned short* Ab = A + (size_t)(row0 + wid * 32 + (lane >> 3)) * ld + (lane & 7) * 8;
    const unsigned short* Bb = BT + (size_t)(col0 + wid * 32 + (lane >> 3)) * ld + (lane & 7) * 8;
    unsigned short* Asd = &As[wid * 32 * 64];
    unsigned short* Bsd = &Bs[wid * 32 * 64];
    f32x4 acc[4][4];
    #pragma unroll
    for (int i = 0; i < 4; ++i)
        #pragma unroll
        for (int j = 0; j < 4; ++j) acc[i][j] = (f32x4){0.f, 0.f, 0.f, 0.f};
    int nkt = kpart >> 6;
    for (int kt = 0; kt < nkt; ++kt) {
        size_t ko = (size_t)kt << 6;
        #pragma unroll
        for (int q = 0; q < 4; ++q) {
            gload_lds16(Ab + (size_t)(q * 8) * ld + ko, Asd + q * 8 * 64);
            gload_lds16(Bb + (size_t)(q * 8) * ld + ko, Bsd + q * 8 * 64);
        }
        __syncthreads();
        #pragma unroll
        for (int kk = 0; kk < 2; ++kk) {
            bf16x8 af[4], bfr[4];
            #pragma unroll
            for (int m = 0; m < 4; ++m)
                af[m] = *(const bf16x8*)(&As[(wr * 64 + m * 16 + (lane & 15)) * 64 + kk * 32 + (lane >> 4) * 8]);
            #pragma unroll
            for (int n = 0; n < 4; ++n)
                bfr[n] = *(const bf16x8*)(&Bs[(wc * 64 + n * 16 + (lane & 15)) * 64 + kk * 32 + (lane >> 4) * 8]);
            #pragma unroll
            for (int m = 0; m < 4; ++m)
                #pragma unroll
                for (int n = 0; n < 4; ++n)
                    acc[m][n] = __builtin_amdgcn_mfma_f32_16x16x32_bf16(af[m], bfr[n], acc[m][n], 0, 0, 0);
        }
        __syncthreads();
    }
    #pragma unroll
    for (int m = 0; m < 4; ++m) {
        int rbase = row0 + wr * 64 + m * 16 + ((lane >> 4) << 2);
        #pragma unroll
        for (int n = 0; n < 4; ++n) {
            int cg = col0 + wc * 64 + n * 16 + (lane & 15);
            float bv = bias[cg];
            #pragma unroll
            for (int r2 = 0; r2 < 4; ++r2) {
                float v = acc[m][n][r2] + bv;
                if (DO_ELU) v = v > 0.f ? v : (__expf(v) - 1.f);
                Out[(size_t)(rbase + r2) * N + cg] = f2bf(v);
            }
        }
    }
}

// ---------------------------------------------------------------------------
// Fused MoE GEMM (r14 schedule + T19 sched_group_barrier read/MFMA pinning):
// 256x256-virtual tile, 8 waves (wave = 128x64v), BK=32 slots, 4-slot LDS
// ring (128 KB), swizzled staging/reads, swapped-operand MFMA. Per iteration
// (2 slots): stage s+2,s+3 -> VM8 (counted) -> barrier -> per slot
// {6 pre-reads | SGB(DS,6); then per m-block: read A(m+2), 4 MFMA,
//  SGB(DS,1)+SGB(MFMA,4)} -- pins an alternating 1-read/4-MFMA emission so
// the LDS port and MFMA pipe overlap instead of convoying.
// 2D XCD map (r12 proven, FETCH 94 MB).
// Epilogue: in-register expert mix -> LDS fp32 partials -> y store direct.
// ---------------------------------------------------------------------------
template<bool DO_ELU, bool OUT_F32>
__global__ __launch_bounds__(512, 1)
void gemm_fused(const unsigned short* __restrict__ A,   // [8192, K]
                const unsigned short* __restrict__ BT,  // [8*dout, K]
                const float* __restrict__ coeffs,       // [8192, 8]
                const float* __restrict__ bias,         // [8*dout]
                void* __restrict__ Out,                 // [8192, dout]
                int K, int dout) {
    __shared__ unsigned short lds[65536];           // 4 x (A 8192 + B 8192)

    // 2D concurrency-aware XCD mapping (r12 proven)
    int bid = blockIdx.x;
    int x = bid & 7;
    int i = bid >> 3;
    int within = i & 15;
    int tm = x * 4 + (within & 3);
    int tn = (i >> 4) * 4 + (within >> 2);
    int row0 = tm << 8;
    int c0 = tn << 5;
    int nkt = K >> 5;

    int t = threadIdx.x;
    int lane = t & 63, wid = t >> 6;
    int wm = wid >> 2, wn = wid & 3;                 // 2x4 waves, each 128x64
    int q = lane >> 4;
    int l15 = lane & 15;

    // fragment ds_read offsets (ushort units), swizzled
    int aoff[8], boff[4];
    #pragma unroll
    for (int m = 0; m < 8; ++m) {
        int row = wm * 128 + m * 16 + l15;
        aoff[m] = row * 32 + ((q ^ ((row >> 1) & 3)) << 3);
    }
    #pragma unroll
    for (int n = 0; n < 4; ++n) {
        int row = wn * 64 + n * 16 + l15;
        boff[n] = 8192 + row * 32 + ((q ^ ((row >> 1) & 3)) << 3);
    }

    // stage source (per-thread, inverse-swizzled column)
    int srow = t >> 2;
    int scol = ((t & 3) ^ ((t >> 3) & 3)) * 8;
    const unsigned short* Asrc = A + (size_t)(row0 + srow) * K + scol;
    // virtual B rows: vr -> BT row (vr>>5)*dout + c0 + (vr&31)
    int br0 = (srow >> 5) * dout + c0 + (srow & 31);            // vr = srow
    int br1 = ((srow + 128) >> 5) * dout + c0 + (srow & 31);    // vr = srow+128
    const unsigned short* Bsrc0 = BT + (size_t)br0 * K + scol;
    const unsigned short* Bsrc1 = BT + (size_t)br1 * K + scol;
    int wdst = wid * 512;                            // wave-uniform dest term

    f32x4 acc[8][4];
    #pragma unroll
    for (int m = 0; m < 8; ++m)
        #pragma unroll
        for (int n = 0; n < 4; ++n) acc[m][n] = (f32x4){0.f, 0.f, 0.f, 0.f};

    // ---- prologue: stage slots 0, 1 ----
    #pragma unroll
    for (int S = 0; S < 2; ++S) {
        gload_lds16(Asrc + S * 32,                   &lds[S * 16384 + wdst]);
        gload_lds16(Asrc + (size_t)128 * K + S * 32, &lds[S * 16384 + 4096 + wdst]);
        gload_lds16(Bsrc0 + S * 32,                  &lds[S * 16384 + 8192 + wdst]);
        gload_lds16(Bsrc1 + S * 32,                  &lds[S * 16384 + 12288 + wdst]);
    }

    for (int s = 0; s < nkt; s += 2) {               // nkt even (18 or 32)
        int sbA = (s & 3) << 14;
        int sbB = ((s + 1) & 3) << 14;
        bool st = (s + 2) < nkt;

        // stage s+2, s+3 FIRST (targets bufs read at s-2: safe; issues early)
        if (st) {
            int rbA = ((s + 2) & 3) << 14;
            int rbB = ((s + 3) & 3) << 14;
            int koA = (s + 2) << 5;
            int koB = (s + 3) << 5;
            gload_lds16(Asrc + koA,                   &lds[rbA + wdst]);
            gload_lds16(Asrc + (size_t)128 * K + koA, &lds[rbA + 4096 + wdst]);
            gload_lds16(Bsrc0 + koA,                  &lds[rbA + 8192 + wdst]);
            gload_lds16(Bsrc1 + koA,                  &lds[rbA + 12288 + wdst]);
            gload_lds16(Asrc + koB,                   &lds[rbB + wdst]);
            gload_lds16(Asrc + (size_t)128 * K + koB, &lds[rbB + 4096 + wdst]);
            gload_lds16(Bsrc0 + koB,                  &lds[rbB + 8192 + wdst]);
            gload_lds16(Bsrc1 + koB,                  &lds[rbB + 12288 + wdst]);
        }
        SB0;
        if (st) { VM8; } else { VM0; }               // drain s,s+1; keep s+2,s+3
        SB0;
        BAR;                                         // all waves' s,s+1 published
        SB0;

        // ---- slot s: pinned 1-read/4-MFMA interleave ----
        {
            bf16x8 bfrg[4], afr[8];
            #pragma unroll
            for (int n = 0; n < 4; ++n)
                bfrg[n] = *(const bf16x8*)(&lds[sbA + boff[n]]);
            afr[0] = *(const bf16x8*)(&lds[sbA + aoff[0]]);
            afr[1] = *(const bf16x8*)(&lds[sbA + aoff[1]]);
            SGB_DS(6);
            __builtin_amdgcn_s_setprio(1);
            #pragma unroll
            for (int m = 0; m < 8; ++m) {
                if (m + 2 < 8)
                    afr[m + 2] = *(const bf16x8*)(&lds[sbA + aoff[m + 2]]);
                #pragma unroll
                for (int n = 0; n < 4; ++n)
                    acc[m][n] = __builtin_amdgcn_mfma_f32_16x16x32_bf16(bfrg[n], afr[m], acc[m][n], 0, 0, 0);
                if (m + 2 < 8) SGB_DS(1);
                SGB_MFMA(4);
            }
            __builtin_amdgcn_s_setprio(0);
        }
        // ---- slot s+1: pinned 1-read/4-MFMA interleave ----
        {
            bf16x8 bfrg[4], afr[8];
            #pragma unroll
            for (int n = 0; n < 4; ++n)
                bfrg[n] = *(const bf16x8*)(&lds[sbB + boff[n]]);
            afr[0] = *(const bf16x8*)(&lds[sbB + aoff[0]]);
            afr[1] = *(const bf16x8*)(&lds[sbB + aoff[1]]);
            SGB_DS(6);
            __builtin_amdgcn_s_setprio(1);
            #pragma unroll
            for (int m = 0; m < 8; ++m) {
                if (m + 2 < 8)
                    afr[m + 2] = *(const bf16x8*)(&lds[sbB + aoff[m + 2]]);
                #pragma unroll
                for (int n = 0; n < 4; ++n)
                    acc[m][n] = __builtin_amdgcn_mfma_f32_16x16x32_bf16(bfrg[n], afr[m], acc[m][n], 0, 0, 0);
                if (m + 2 < 8) SGB_DS(1);
                SGB_MFMA(4);
            }
            __builtin_amdgcn_s_setprio(0);
        }
        SB0;
    }

    // ======== epilogue phase 1: per-wave expert mix -> LDS fp32 partials ===
    float* plds = (float*)lds;                       // 8 regions x [128][32] f32
    __syncthreads();                                 // ring fully consumed
    {
        int e0 = 2 * wn, e1 = e0 + 1;
        f32x4 b0h[2], b1h[2];
        #pragma unroll
        for (int h = 0; h < 2; ++h) {
            float4 u0 = *(const float4*)(bias + e0 * dout + c0 + h * 16 + q * 4);
            float4 u1 = *(const float4*)(bias + e1 * dout + c0 + h * 16 + q * 4);
            b0h[h] = (f32x4){u0.x, u0.y, u0.z, u0.w};
            b1h[h] = (f32x4){u1.x, u1.y, u1.z, u1.w};
        }
        float* preg = plds + (wid << 12);
        #pragma unroll
        for (int m = 0; m < 8; ++m) {
            int grow = row0 + wm * 128 + m * 16 + l15;
            float c8 = coeffs[(size_t)grow * 8 + e0];
            float c9 = coeffs[(size_t)grow * 8 + e1];
            #pragma unroll
            for (int h = 0; h < 2; ++h) {
                f32x4 z0 = acc[m][h];
                f32x4 z1 = acc[m][h + 2];
                f32x4 p;
                #pragma unroll
                for (int r = 0; r < 4; ++r)
                    p[r] = c8 * (z0[r] + b0h[h][r]) + c9 * (z1[r] + b1h[h][r]);
                int row = m * 16 + l15;
                int slot = (h * 4 + q) ^ (row & 7);
                *(f32x4*)(preg + row * 32 + (slot << 2)) = p;
            }
        }
    }
    __syncthreads();

    // ======== epilogue phase 2: sum 4 wn-partials, act, store ==============
    {
        int r2 = t >> 1;                             // tile row 0..255
        int ch = t & 1;                              // col half (16 cols)
        int wmr = r2 >> 7;
        int rr = r2 & 127;
        int sw = rr & 7;
        size_t obase = (size_t)(row0 + r2) * dout + c0 + ch * 16;
        #pragma unroll
        for (int sl = 0; sl < 4; ++sl) {
            int L = ch * 4 + sl;
            int phys = L ^ sw;
            f32x4 sum = (f32x4){0.f, 0.f, 0.f, 0.f};
            #pragma unroll
            for (int w2 = 0; w2 < 4; ++w2) {
                const f32x4 v = *(const f32x4*)(plds + (((wmr << 2) + w2) << 12) + rr * 32 + (phys << 2));
                sum[0] += v[0]; sum[1] += v[1]; sum[2] += v[2]; sum[3] += v[3];
            }
            if (DO_ELU) {
                #pragma unroll
                for (int r = 0; r < 4; ++r)
                    sum[r] = sum[r] > 0.f ? sum[r] : (__expf(sum[r]) - 1.f);
            }
            if (OUT_F32) {
                float4 o = {sum[0], sum[1], sum[2], sum[3]};
                *(float4*)((float*)Out + obase + sl * 4) = o;
            } else {
                ushort4 o;
                o.x = f2bf(sum[0]); o.y = f2bf(sum[1]);
                o.z = f2bf(sum[2]); o.w = f2bf(sum[3]);
                *(ushort4*)((unsigned short*)Out + obase + sl * 4) = o;
            }
        }
    }
}

// ---------------------------------------------------------------------------
extern "C" void kernel_launch(void* const* d_in, const int* in_sizes, int n_in,
                              void* d_out, int out_size, void* d_ws, size_t ws_size,
                              hipStream_t stream) {
    const float* motion  = (const float*)d_in[0];
    const float* command = (const float*)d_in[1];
    const float* g_w1 = (const float*)d_in[2];
    const float* g_b1 = (const float*)d_in[3];
    const float* g_w2 = (const float*)d_in[4];
    const float* g_b2 = (const float*)d_in[5];
    const float* g_w3 = (const float*)d_in[6];
    const float* g_b3 = (const float*)d_in[7];
    const float* w[6]  = {(const float*)d_in[8],  (const float*)d_in[10],
                          (const float*)d_in[12], (const float*)d_in[14],
                          (const float*)d_in[16], (const float*)d_in[18]};
    const float* bb[6] = {(const float*)d_in[9],  (const float*)d_in[11],
                          (const float*)d_in[13], (const float*)d_in[15],
                          (const float*)d_in[17], (const float*)d_in[19]};

    char* ws = (char*)d_ws;
    unsigned short* xc0  = (unsigned short*)ws;                 //  9,437,184
    unsigned short* actA = (unsigned short*)(ws + 9437184);     // 16,777,216
    unsigned short* actB = (unsigned short*)(ws + 26214400);    // 16,777,216
    float* coeffs        = (float*)(ws + 42991616);             //    262,144
    unsigned short* wT   = (unsigned short*)(ws + 43253760);    // 16,777,216

    // 1. concat + convert input
    concat_cvt<<<4608, 256, 0, stream>>>(motion, command, xc0);

    // 2. gating network
    transpose_cvt<<<144, 256, 0, stream>>>(g_w1, wT, 576, 1024, 144);
    gemm_bf16<true><<<512, 256, 0, stream>>>(xc0, wT, g_b1, actA, 1024, 576, 576);
    transpose_cvt<<<256, 256, 0, stream>>>(g_w2, wT, 1024, 1024, 256);
    gemm_bf16<true><<<512, 256, 0, stream>>>(actA, wT, g_b2, actB, 1024, 1024, 1024);
    gating_kernel<<<2048, 256, 0, stream>>>(actB, g_w3, g_b3, coeffs);

    // 3. MoE layer 0: K=576 (nkt=18), dout=1024 -> actA
    transpose_cvt<<<1152, 256, 0, stream>>>(w[0], wT, 576, 1024, 144);
    gemm_fused<true, false><<<1024, 512, 0, stream>>>(
        xc0, wT, coeffs, bb[0], actA, 576, 1024);

    // 4. MoE layers 1..4: K=1024 (nkt=32), dout=1024, ping-pong actA/actB
    unsigned short* bufs[2] = {actA, actB};
    for (int l = 1; l <= 4; ++l) {
        unsigned short* in  = bufs[(l + 1) & 1];
        unsigned short* out = bufs[l & 1];
        transpose_cvt<<<2048, 256, 0, stream>>>(w[l], wT, 1024, 1024, 256);
        gemm_fused<true, false><<<1024, 512, 0, stream>>>(
            in, wT, coeffs, bb[l], out, 1024, 1024);
    }

    // 5. MoE layer 5: K=1024, dout=512, fp32 out
    transpose_cvt<<<1024, 256, 0, stream>>>(w[5], wT, 1024, 512, 128);
    gemm_fused<false, true><<<512, 512, 0, stream>>>(
        actA, wT, coeffs, bb[5], d_out, 1024, 512);
}

// Round 20
// 694.534 us; speedup vs baseline: 1.2302x; 1.0108x over previous
//
#include <hip/hip_runtime.h>
#include <hip/hip_bf16.h>

typedef __attribute__((ext_vector_type(8))) short bf16x8;
typedef __attribute__((ext_vector_type(4))) float f32x4;

__device__ __forceinline__ float bf2f(unsigned short u) {
    union { unsigned int i; float f; } v; v.i = ((unsigned int)u) << 16; return v.f;
}
__device__ __forceinline__ unsigned short f2bf(float f) {
    union { float f; unsigned int i; } v; v.f = f;
    unsigned int x = v.i;
    return (unsigned short)((x + 0x7FFFu + ((x >> 16) & 1u)) >> 16);
}

__device__ __forceinline__ void gload_lds16(const unsigned short* g, unsigned short* l) {
    __builtin_amdgcn_global_load_lds(
        (const __attribute__((address_space(1))) unsigned int*)g,
        (__attribute__((address_space(3))) unsigned int*)l,
        16, 0, 0);
}

#define VM8  asm volatile("s_waitcnt vmcnt(8)" ::: "memory")
#define VM0  asm volatile("s_waitcnt vmcnt(0)" ::: "memory")
#define SB0  __builtin_amdgcn_sched_barrier(0)
#define BAR  __builtin_amdgcn_s_barrier()
#define SGB_DS(n)   __builtin_amdgcn_sched_group_barrier(0x100, (n), 0)
#define SGB_MFMA(n) __builtin_amdgcn_sched_group_barrier(0x008, (n), 0)

// ---------------------------------------------------------------------------
// concat(motion, command) -> bf16 [8192, 576]
// ---------------------------------------------------------------------------
__global__ void concat_cvt(const float* __restrict__ motion,
                           const float* __restrict__ command,
                           unsigned short* __restrict__ out) {
    int id = blockIdx.x * 256 + threadIdx.x;
    int b = id / 144, q = id % 144;
    float4 v;
    if (q < 128) v = *(const float4*)(motion + (size_t)b * 512 + q * 4);
    else         v = *(const float4*)(command + (size_t)b * 64 + (q - 128) * 4);
    ushort4 o;
    o.x = f2bf(v.x); o.y = f2bf(v.y); o.z = f2bf(v.z); o.w = f2bf(v.w);
    *(ushort4*)(out + (size_t)b * 576 + q * 4) = o;
}

// ---------------------------------------------------------------------------
// batched fp32 [K,N] -> bf16 [N,K] per expert (tpe = 64x64 tiles per expert)
// ---------------------------------------------------------------------------
__global__ void transpose_cvt(const float* __restrict__ in,
                              unsigned short* __restrict__ out,
                              int K, int N, int tpe) {
    __shared__ unsigned short tile[64][72];
    int e = blockIdx.x / tpe, r = blockIdx.x % tpe;
    in  += (size_t)e * K * N;
    out += (size_t)e * N * K;
    int nbn = N / 64;
    int k0 = (r / nbn) * 64;
    int n0 = (r % nbn) * 64;
    int t = threadIdx.x;
    int tx = t & 63, ty = t >> 6;
    #pragma unroll
    for (int rr = 0; rr < 16; ++rr) {
        int kr = ty + rr * 4;
        tile[kr][tx] = f2bf(in[(size_t)(k0 + kr) * N + n0 + tx]);
    }
    __syncthreads();
    int txh = t & 31, tyh = t >> 5;
    #pragma unroll
    for (int rr = 0; rr < 8; ++rr) {
        int nr = tyh + rr * 8;
        unsigned int vlo = tile[2 * txh][nr];
        unsigned int vhi = tile[2 * txh + 1][nr];
        unsigned int* o32 = (unsigned int*)(out + (size_t)(n0 + nr) * K + k0);
        o32[txh] = vlo | (vhi << 16);
    }
}

// ---------------------------------------------------------------------------
// gating final: coeffs = softmax(g2 @ w3 + b3)
// ---------------------------------------------------------------------------
__global__ __launch_bounds__(256) void gating_kernel(
    const unsigned short* __restrict__ g2,
    const float* __restrict__ w3, const float* __restrict__ b3,
    float* __restrict__ coeffs) {
    __shared__ float w3s[8][1024];
    int t = threadIdx.x;
    for (int i = t; i < 1024; i += 256) {
        #pragma unroll
        for (int e = 0; e < 8; ++e) w3s[e][i] = w3[(size_t)i * 8 + e];
    }
    __syncthreads();
    int lane = t & 63, wv = t >> 6;
    int row = blockIdx.x * 4 + wv;
    const unsigned short* xr = g2 + (size_t)row * 1024;
    float acc[8];
    #pragma unroll
    for (int e = 0; e < 8; ++e) acc[e] = 0.f;
    for (int it = 0; it < 16; ++it) {
        float xv = bf2f(xr[lane + it * 64]);
        #pragma unroll
        for (int e = 0; e < 8; ++e) acc[e] += xv * w3s[e][lane + it * 64];
    }
    #pragma unroll
    for (int e = 0; e < 8; ++e) {
        float v = acc[e];
        #pragma unroll
        for (int off = 32; off; off >>= 1) v += __shfl_xor(v, off);
        acc[e] = v + b3[e];
    }
    float mx = acc[0];
    #pragma unroll
    for (int e = 1; e < 8; ++e) mx = fmaxf(mx, acc[e]);
    float s = 0.f;
    #pragma unroll
    for (int e = 0; e < 8; ++e) { acc[e] = __expf(acc[e] - mx); s += acc[e]; }
    float inv = 1.f / s;
    if (lane < 8) coeffs[(size_t)row * 8 + lane] = acc[lane] * inv;
}

// ---------------------------------------------------------------------------
// gating GEMM (proven): 128x128x64, global_load_lds both operands, 4 blk/CU
// ---------------------------------------------------------------------------
template<bool DO_ELU>
__global__ __launch_bounds__(256, 4)
void gemm_bf16(const unsigned short* __restrict__ A,
               const unsigned short* __restrict__ BT,
               const float* __restrict__ bias,
               unsigned short* __restrict__ Out,
               int N, int ld, int kpart) {
    __shared__ unsigned short As[128 * 64];
    __shared__ unsigned short Bs[128 * 64];
    int ntn = N >> 7;
    int nwg = gridDim.x;
    int bid = blockIdx.x;
    { int cpx = nwg >> 3; bid = (bid & 7) * cpx + (bid >> 3); }
    int tm = bid / ntn, tn = bid - tm * ntn;
    int row0 = tm << 7, col0 = tn << 7;
    int t = threadIdx.x;
    int lane = t & 63;
    int wid = t >> 6;
    int wr = wid >> 1, wc = wid & 1;
    const unsigned short* Ab = A + (size_t)(row0 + wid * 32 + (lane >> 3)) * ld + (lane & 7) * 8;
    const unsigned short* Bb = BT + (size_t)(col0 + wid * 32 + (lane >> 3)) * ld + (lane & 7) * 8;
    unsigned short* Asd = &As[wid * 32 * 64];
    unsigned short* Bsd = &Bs[wid * 32 * 64];
    f32x4 acc[4][4];
    #pragma unroll
    for (int i = 0; i < 4; ++i)
        #pragma unroll
        for (int j = 0; j < 4; ++j) acc[i][j] = (f32x4){0.f, 0.f, 0.f, 0.f};
    int nkt = kpart >> 6;
    for (int kt = 0; kt < nkt; ++kt) {
        size_t ko = (size_t)kt << 6;
        #pragma unroll
        for (int q = 0; q < 4; ++q) {
            gload_lds16(Ab + (size_t)(q * 8) * ld + ko, Asd + q * 8 * 64);
            gload_lds16(Bb + (size_t)(q * 8) * ld + ko, Bsd + q * 8 * 64);
        }
        __syncthreads();
        #pragma unroll
        for (int kk = 0; kk < 2; ++kk) {
            bf16x8 af[4], bfr[4];
            #pragma unroll
            for (int m = 0; m < 4; ++m)
                af[m] = *(const bf16x8*)(&As[(wr * 64 + m * 16 + (lane & 15)) * 64 + kk * 32 + (lane >> 4) * 8]);
            #pragma unroll
            for (int n = 0; n < 4; ++n)
                bfr[n] = *(const bf16x8*)(&Bs[(wc * 64 + n * 16 + (lane & 15)) * 64 + kk * 32 + (lane >> 4) * 8]);
            #pragma unroll
            for (int m = 0; m < 4; ++m)
                #pragma unroll
                for (int n = 0; n < 4; ++n)
                    acc[m][n] = __builtin_amdgcn_mfma_f32_16x16x32_bf16(af[m], bfr[n], acc[m][n], 0, 0, 0);
        }
        __syncthreads();
    }
    #pragma unroll
    for (int m = 0; m < 4; ++m) {
        int rbase = row0 + wr * 64 + m * 16 + ((lane >> 4) << 2);
        #pragma unroll
        for (int n = 0; n < 4; ++n) {
            int cg = col0 + wc * 64 + n * 16 + (lane & 15);
            float bv = bias[cg];
            #pragma unroll
            for (int r2 = 0; r2 < 4; ++r2) {
                float v = acc[m][n][r2] + bv;
                if (DO_ELU) v = v > 0.f ? v : (__expf(v) - 1.f);
                Out[(size_t)(rbase + r2) * N + cg] = f2bf(v);
            }
        }
    }
}

// ---------------------------------------------------------------------------
// Fused MoE GEMM (r19 + cross-slot SGB pipeline): 256x256-virtual tile,
// 8 waves (wave = 128x64v), BK=32 slots, 4-slot LDS ring (128 KB), swizzled
// staging/reads, swapped-operand MFMA. Per iteration (2 slots): stage
// s+2,s+3 -> VM8 (counted) -> barrier -> merged 2-slot compute with SGB-
// pinned reads: pre-read 8 (B(s)+A0-3(s)); slot-s m-blocks carry A4-7(s)
// then B(s+1)+A0-3(s+1) pairs; slot-s+1 m-blocks carry A4-7(s+1) then a
// pure-MFMA tail. Every A-frag has a 4-m-block (~16 MFMA) read->use
// distance; LDS port stays busy through the MFMA stream.
// 2D XCD map (r12 proven, FETCH 94 MB).
// Epilogue: in-register expert mix -> LDS fp32 partials -> y store direct.
// ---------------------------------------------------------------------------
template<bool DO_ELU, bool OUT_F32>
__global__ __launch_bounds__(512, 1)
void gemm_fused(const unsigned short* __restrict__ A,   // [8192, K]
                const unsigned short* __restrict__ BT,  // [8*dout, K]
                const float* __restrict__ coeffs,       // [8192, 8]
                const float* __restrict__ bias,         // [8*dout]
                void* __restrict__ Out,                 // [8192, dout]
                int K, int dout) {
    __shared__ unsigned short lds[65536];           // 4 x (A 8192 + B 8192)

    // 2D concurrency-aware XCD mapping (r12 proven)
    int bid = blockIdx.x;
    int x = bid & 7;
    int i = bid >> 3;
    int within = i & 15;
    int tm = x * 4 + (within & 3);
    int tn = (i >> 4) * 4 + (within >> 2);
    int row0 = tm << 8;
    int c0 = tn << 5;
    int nkt = K >> 5;

    int t = threadIdx.x;
    int lane = t & 63, wid = t >> 6;
    int wm = wid >> 2, wn = wid & 3;                 // 2x4 waves, each 128x64
    int q = lane >> 4;
    int l15 = lane & 15;

    // fragment ds_read offsets (ushort units), swizzled
    int aoff[8], boff[4];
    #pragma unroll
    for (int m = 0; m < 8; ++m) {
        int row = wm * 128 + m * 16 + l15;
        aoff[m] = row * 32 + ((q ^ ((row >> 1) & 3)) << 3);
    }
    #pragma unroll
    for (int n = 0; n < 4; ++n) {
        int row = wn * 64 + n * 16 + l15;
        boff[n] = 8192 + row * 32 + ((q ^ ((row >> 1) & 3)) << 3);
    }

    // stage source (per-thread, inverse-swizzled column)
    int srow = t >> 2;
    int scol = ((t & 3) ^ ((t >> 3) & 3)) * 8;
    const unsigned short* Asrc = A + (size_t)(row0 + srow) * K + scol;
    // virtual B rows: vr -> BT row (vr>>5)*dout + c0 + (vr&31)
    int br0 = (srow >> 5) * dout + c0 + (srow & 31);            // vr = srow
    int br1 = ((srow + 128) >> 5) * dout + c0 + (srow & 31);    // vr = srow+128
    const unsigned short* Bsrc0 = BT + (size_t)br0 * K + scol;
    const unsigned short* Bsrc1 = BT + (size_t)br1 * K + scol;
    int wdst = wid * 512;                            // wave-uniform dest term

    f32x4 acc[8][4];
    #pragma unroll
    for (int m = 0; m < 8; ++m)
        #pragma unroll
        for (int n = 0; n < 4; ++n) acc[m][n] = (f32x4){0.f, 0.f, 0.f, 0.f};

    // ---- prologue: stage slots 0, 1 ----
    #pragma unroll
    for (int S = 0; S < 2; ++S) {
        gload_lds16(Asrc + S * 32,                   &lds[S * 16384 + wdst]);
        gload_lds16(Asrc + (size_t)128 * K + S * 32, &lds[S * 16384 + 4096 + wdst]);
        gload_lds16(Bsrc0 + S * 32,                  &lds[S * 16384 + 8192 + wdst]);
        gload_lds16(Bsrc1 + S * 32,                  &lds[S * 16384 + 12288 + wdst]);
    }

    for (int s = 0; s < nkt; s += 2) {               // nkt even (18 or 32)
        int sbA = (s & 3) << 14;
        int sbB = ((s + 1) & 3) << 14;
        bool st = (s + 2) < nkt;

        // stage s+2, s+3 FIRST (targets bufs read at s-2: safe; issues early)
        if (st) {
            int rbA = ((s + 2) & 3) << 14;
            int rbB = ((s + 3) & 3) << 14;
            int koA = (s + 2) << 5;
            int koB = (s + 3) << 5;
            gload_lds16(Asrc + koA,                   &lds[rbA + wdst]);
            gload_lds16(Asrc + (size_t)128 * K + koA, &lds[rbA + 4096 + wdst]);
            gload_lds16(Bsrc0 + koA,                  &lds[rbA + 8192 + wdst]);
            gload_lds16(Bsrc1 + koA,                  &lds[rbA + 12288 + wdst]);
            gload_lds16(Asrc + koB,                   &lds[rbB + wdst]);
            gload_lds16(Asrc + (size_t)128 * K + koB, &lds[rbB + 4096 + wdst]);
            gload_lds16(Bsrc0 + koB,                  &lds[rbB + 8192 + wdst]);
            gload_lds16(Bsrc1 + koB,                  &lds[rbB + 12288 + wdst]);
        }
        SB0;
        if (st) { VM8; } else { VM0; }               // drain s,s+1; keep s+2,s+3
        SB0;
        BAR;                                         // all waves' s,s+1 published
        SB0;

        // ---- merged 2-slot compute with cross-slot pinned reads ----
        {
            bf16x8 bA[4], aA[8], bB[4], aB[8];
            // pre-reads: B(s) + A0-3(s)
            #pragma unroll
            for (int n = 0; n < 4; ++n)
                bA[n] = *(const bf16x8*)(&lds[sbA + boff[n]]);
            #pragma unroll
            for (int m = 0; m < 4; ++m)
                aA[m] = *(const bf16x8*)(&lds[sbA + aoff[m]]);
            SGB_DS(8);
            __builtin_amdgcn_s_setprio(1);
            // slot s m-blocks
            #pragma unroll
            for (int m = 0; m < 8; ++m) {
                if (m < 4) {
                    aA[m + 4] = *(const bf16x8*)(&lds[sbA + aoff[m + 4]]);
                } else {
                    bB[m - 4] = *(const bf16x8*)(&lds[sbB + boff[m - 4]]);
                    aB[m - 4] = *(const bf16x8*)(&lds[sbB + aoff[m - 4]]);
                }
                #pragma unroll
                for (int n = 0; n < 4; ++n)
                    acc[m][n] = __builtin_amdgcn_mfma_f32_16x16x32_bf16(bA[n], aA[m], acc[m][n], 0, 0, 0);
                if (m < 4) { SGB_DS(1); } else { SGB_DS(2); }
                SGB_MFMA(4);
            }
            // slot s+1 m-blocks
            #pragma unroll
            for (int m = 0; m < 8; ++m) {
                if (m < 4) {
                    aB[m + 4] = *(const bf16x8*)(&lds[sbB + aoff[m + 4]]);
                }
                #pragma unroll
                for (int n = 0; n < 4; ++n)
                    acc[m][n] = __builtin_amdgcn_mfma_f32_16x16x32_bf16(bB[n], aB[m], acc[m][n], 0, 0, 0);
                if (m < 4) { SGB_DS(1); }
                SGB_MFMA(4);
            }
            __builtin_amdgcn_s_setprio(0);
        }
        SB0;
    }

    // ======== epilogue phase 1: per-wave expert mix -> LDS fp32 partials ===
    float* plds = (float*)lds;                       // 8 regions x [128][32] f32
    __syncthreads();                                 // ring fully consumed
    {
        int e0 = 2 * wn, e1 = e0 + 1;
        f32x4 b0h[2], b1h[2];
        #pragma unroll
        for (int h = 0; h < 2; ++h) {
            float4 u0 = *(const float4*)(bias + e0 * dout + c0 + h * 16 + q * 4);
            float4 u1 = *(const float4*)(bias + e1 * dout + c0 + h * 16 + q * 4);
            b0h[h] = (f32x4){u0.x, u0.y, u0.z, u0.w};
            b1h[h] = (f32x4){u1.x, u1.y, u1.z, u1.w};
        }
        float* preg = plds + (wid << 12);
        #pragma unroll
        for (int m = 0; m < 8; ++m) {
            int grow = row0 + wm * 128 + m * 16 + l15;
            float c8 = coeffs[(size_t)grow * 8 + e0];
            float c9 = coeffs[(size_t)grow * 8 + e1];
            #pragma unroll
            for (int h = 0; h < 2; ++h) {
                f32x4 z0 = acc[m][h];
                f32x4 z1 = acc[m][h + 2];
                f32x4 p;
                #pragma unroll
                for (int r = 0; r < 4; ++r)
                    p[r] = c8 * (z0[r] + b0h[h][r]) + c9 * (z1[r] + b1h[h][r]);
                int row = m * 16 + l15;
                int slot = (h * 4 + q) ^ (row & 7);
                *(f32x4*)(preg + row * 32 + (slot << 2)) = p;
            }
        }
    }
    __syncthreads();

    // ======== epilogue phase 2: sum 4 wn-partials, act, store ==============
    {
        int r2 = t >> 1;                             // tile row 0..255
        int ch = t & 1;                              // col half (16 cols)
        int wmr = r2 >> 7;
        int rr = r2 & 127;
        int sw = rr & 7;
        size_t obase = (size_t)(row0 + r2) * dout + c0 + ch * 16;
        #pragma unroll
        for (int sl = 0; sl < 4; ++sl) {
            int L = ch * 4 + sl;
            int phys = L ^ sw;
            f32x4 sum = (f32x4){0.f, 0.f, 0.f, 0.f};
            #pragma unroll
            for (int w2 = 0; w2 < 4; ++w2) {
                const f32x4 v = *(const f32x4*)(plds + (((wmr << 2) + w2) << 12) + rr * 32 + (phys << 2));
                sum[0] += v[0]; sum[1] += v[1]; sum[2] += v[2]; sum[3] += v[3];
            }
            if (DO_ELU) {
                #pragma unroll
                for (int r = 0; r < 4; ++r)
                    sum[r] = sum[r] > 0.f ? sum[r] : (__expf(sum[r]) - 1.f);
            }
            if (OUT_F32) {
                float4 o = {sum[0], sum[1], sum[2], sum[3]};
                *(float4*)((float*)Out + obase + sl * 4) = o;
            } else {
                ushort4 o;
                o.x = f2bf(sum[0]); o.y = f2bf(sum[1]);
                o.z = f2bf(sum[2]); o.w = f2bf(sum[3]);
                *(ushort4*)((unsigned short*)Out + obase + sl * 4) = o;
            }
        }
    }
}

// ---------------------------------------------------------------------------
extern "C" void kernel_launch(void* const* d_in, const int* in_sizes, int n_in,
                              void* d_out, int out_size, void* d_ws, size_t ws_size,
                              hipStream_t stream) {
    const float* motion  = (const float*)d_in[0];
    const float* command = (const float*)d_in[1];
    const float* g_w1 = (const float*)d_in[2];
    const float* g_b1 = (const float*)d_in[3];
    const float* g_w2 = (const float*)d_in[4];
    const float* g_b2 = (const float*)d_in[5];
    const float* g_w3 = (const float*)d_in[6];
    const float* g_b3 = (const float*)d_in[7];
    const float* w[6]  = {(const float*)d_in[8],  (const float*)d_in[10],
                          (const float*)d_in[12], (const float*)d_in[14],
                          (const float*)d_in[16], (const float*)d_in[18]};
    const float* bb[6] = {(const float*)d_in[9],  (const float*)d_in[11],
                          (const float*)d_in[13], (const float*)d_in[15],
                          (const float*)d_in[17], (const float*)d_in[19]};

    char* ws = (char*)d_ws;
    unsigned short* xc0  = (unsigned short*)ws;                 //  9,437,184
    unsigned short* actA = (unsigned short*)(ws + 9437184);     // 16,777,216
    unsigned short* actB = (unsigned short*)(ws + 26214400);    // 16,777,216
    float* coeffs        = (float*)(ws + 42991616);             //    262,144
    unsigned short* wT   = (unsigned short*)(ws + 43253760);    // 16,777,216

    // 1. concat + convert input
    concat_cvt<<<4608, 256, 0, stream>>>(motion, command, xc0);

    // 2. gating network
    transpose_cvt<<<144, 256, 0, stream>>>(g_w1, wT, 576, 1024, 144);
    gemm_bf16<true><<<512, 256, 0, stream>>>(xc0, wT, g_b1, actA, 1024, 576, 576);
    transpose_cvt<<<256, 256, 0, stream>>>(g_w2, wT, 1024, 1024, 256);
    gemm_bf16<true><<<512, 256, 0, stream>>>(actA, wT, g_b2, actB, 1024, 1024, 1024);
    gating_kernel<<<2048, 256, 0, stream>>>(actB, g_w3, g_b3, coeffs);

    // 3. MoE layer 0: K=576 (nkt=18), dout=1024 -> actA
    transpose_cvt<<<1152, 256, 0, stream>>>(w[0], wT, 576, 1024, 144);
    gemm_fused<true, false><<<1024, 512, 0, stream>>>(
        xc0, wT, coeffs, bb[0], actA, 576, 1024);

    // 4. MoE layers 1..4: K=1024 (nkt=32), dout=1024, ping-pong actA/actB
    unsigned short* bufs[2] = {actA, actB};
    for (int l = 1; l <= 4; ++l) {
        unsigned short* in  = bufs[(l + 1) & 1];
        unsigned short* out = bufs[l & 1];
        transpose_cvt<<<2048, 256, 0, stream>>>(w[l], wT, 1024, 1024, 256);
        gemm_fused<true, false><<<1024, 512, 0, stream>>>(
            in, wT, coeffs, bb[l], out, 1024, 1024);
    }

    // 5. MoE layer 5: K=1024, dout=512, fp32 out
    transpose_cvt<<<1024, 256, 0, stream>>>(w[5], wT, 1024, 512, 128);
    gemm_fused<false, true><<<512, 512, 0, stream>>>(
        actA, wT, coeffs, bb[5], d_out, 1024, 512);
}

// Round 21
// 678.140 us; speedup vs baseline: 1.2600x; 1.0242x over previous
//
#include <hip/hip_runtime.h>
#include <hip/hip_bf16.h>

typedef __attribute__((ext_vector_type(8))) short bf16x8;
typedef __attribute__((ext_vector_type(4))) float f32x4;

__device__ __forceinline__ float bf2f(unsigned short u) {
    union { unsigned int i; float f; } v; v.i = ((unsigned int)u) << 16; return v.f;
}
__device__ __forceinline__ unsigned short f2bf(float f) {
    union { float f; unsigned int i; } v; v.f = f;
    unsigned int x = v.i;
    return (unsigned short)((x + 0x7FFFu + ((x >> 16) & 1u)) >> 16);
}

__device__ __forceinline__ void gload_lds16(const unsigned short* g, unsigned short* l) {
    __builtin_amdgcn_global_load_lds(
        (const __attribute__((address_space(1))) unsigned int*)g,
        (__attribute__((address_space(3))) unsigned int*)l,
        16, 0, 0);
}

#define VM8  asm volatile("s_waitcnt vmcnt(8)" ::: "memory")
#define VM0  asm volatile("s_waitcnt vmcnt(0)" ::: "memory")
#define SB0  __builtin_amdgcn_sched_barrier(0)
#define BAR  __builtin_amdgcn_s_barrier()
#define SGB_DS(n)   __builtin_amdgcn_sched_group_barrier(0x100, (n), 0)
#define SGB_MFMA(n) __builtin_amdgcn_sched_group_barrier(0x008, (n), 0)

// ---------------------------------------------------------------------------
// concat(motion, command) -> bf16 [8192, 576]
// ---------------------------------------------------------------------------
__global__ void concat_cvt(const float* __restrict__ motion,
                           const float* __restrict__ command,
                           unsigned short* __restrict__ out) {
    int id = blockIdx.x * 256 + threadIdx.x;
    int b = id / 144, q = id % 144;
    float4 v;
    if (q < 128) v = *(const float4*)(motion + (size_t)b * 512 + q * 4);
    else         v = *(const float4*)(command + (size_t)b * 64 + (q - 128) * 4);
    ushort4 o;
    o.x = f2bf(v.x); o.y = f2bf(v.y); o.z = f2bf(v.z); o.w = f2bf(v.w);
    *(ushort4*)(out + (size_t)b * 576 + q * 4) = o;
}

// ---------------------------------------------------------------------------
// device transpose tile worker: fp32 [K,N] (+e offset) -> bf16 [N,K]
// ---------------------------------------------------------------------------
__device__ __forceinline__ void transp_tile(const float* in, unsigned short* out,
                                            int K, int N, int tpe, int rel, int t) {
    __shared__ unsigned short tile[64][72];
    int e = rel / tpe, r = rel % tpe;
    in  += (size_t)e * K * N;
    out += (size_t)e * N * K;
    int nbn = N / 64;
    int k0 = (r / nbn) * 64;
    int n0 = (r % nbn) * 64;
    int tx = t & 63, ty = t >> 6;
    #pragma unroll
    for (int rr = 0; rr < 16; ++rr) {
        int kr = ty + rr * 4;
        tile[kr][tx] = f2bf(in[(size_t)(k0 + kr) * N + n0 + tx]);
    }
    __syncthreads();
    int txh = t & 31, tyh = t >> 5;
    #pragma unroll
    for (int rr = 0; rr < 8; ++rr) {
        int nr = tyh + rr * 8;
        unsigned int vlo = tile[2 * txh][nr];
        unsigned int vhi = tile[2 * txh + 1][nr];
        unsigned int* o32 = (unsigned int*)(out + (size_t)(n0 + nr) * K + k0);
        o32[txh] = vlo | (vhi << 16);
    }
}

// ---------------------------------------------------------------------------
// ONE dispatch for ALL 8 weight transposes (2 gating + 6 MoE) -> full GPU
// occupancy, no launch gaps. Block ranges:
// [0,144) g_w1 | [144,400) g_w2 | [400,1552) w0 | [1552,3600) w1 |
// [3600,5648) w2 | [5648,7696) w3 | [7696,9744) w4 | [9744,10768) w5
// ---------------------------------------------------------------------------
__global__ __launch_bounds__(256)
void transpose_all(const float* __restrict__ g_w1, const float* __restrict__ g_w2,
                   const float* __restrict__ w0, const float* __restrict__ w1,
                   const float* __restrict__ w2, const float* __restrict__ w3,
                   const float* __restrict__ w4, const float* __restrict__ w5,
                   unsigned short* __restrict__ tg1, unsigned short* __restrict__ tg2,
                   unsigned short* __restrict__ t0, unsigned short* __restrict__ t1,
                   unsigned short* __restrict__ t2, unsigned short* __restrict__ t3,
                   unsigned short* __restrict__ t4, unsigned short* __restrict__ t5) {
    int b = blockIdx.x;
    int t = threadIdx.x;
    if (b < 144)        transp_tile(g_w1, tg1, 576, 1024, 144, b, t);
    else if (b < 400)   transp_tile(g_w2, tg2, 1024, 1024, 256, b - 144, t);
    else if (b < 1552)  transp_tile(w0, t0, 576, 1024, 144, b - 400, t);
    else if (b < 3600)  transp_tile(w1, t1, 1024, 1024, 256, b - 1552, t);
    else if (b < 5648)  transp_tile(w2, t2, 1024, 1024, 256, b - 3600, t);
    else if (b < 7696)  transp_tile(w3, t3, 1024, 1024, 256, b - 5648, t);
    else if (b < 9744)  transp_tile(w4, t4, 1024, 1024, 256, b - 7696, t);
    else                transp_tile(w5, t5, 1024, 512, 128, b - 9744, t);
}

// ---------------------------------------------------------------------------
// gating final: coeffs = softmax(g2 @ w3 + b3)
// ---------------------------------------------------------------------------
__global__ __launch_bounds__(256) void gating_kernel(
    const unsigned short* __restrict__ g2,
    const float* __restrict__ w3, const float* __restrict__ b3,
    float* __restrict__ coeffs) {
    __shared__ float w3s[8][1024];
    int t = threadIdx.x;
    for (int i = t; i < 1024; i += 256) {
        #pragma unroll
        for (int e = 0; e < 8; ++e) w3s[e][i] = w3[(size_t)i * 8 + e];
    }
    __syncthreads();
    int lane = t & 63, wv = t >> 6;
    int row = blockIdx.x * 4 + wv;
    const unsigned short* xr = g2 + (size_t)row * 1024;
    float acc[8];
    #pragma unroll
    for (int e = 0; e < 8; ++e) acc[e] = 0.f;
    for (int it = 0; it < 16; ++it) {
        float xv = bf2f(xr[lane + it * 64]);
        #pragma unroll
        for (int e = 0; e < 8; ++e) acc[e] += xv * w3s[e][lane + it * 64];
    }
    #pragma unroll
    for (int e = 0; e < 8; ++e) {
        float v = acc[e];
        #pragma unroll
        for (int off = 32; off; off >>= 1) v += __shfl_xor(v, off);
        acc[e] = v + b3[e];
    }
    float mx = acc[0];
    #pragma unroll
    for (int e = 1; e < 8; ++e) mx = fmaxf(mx, acc[e]);
    float s = 0.f;
    #pragma unroll
    for (int e = 0; e < 8; ++e) { acc[e] = __expf(acc[e] - mx); s += acc[e]; }
    float inv = 1.f / s;
    if (lane < 8) coeffs[(size_t)row * 8 + lane] = acc[lane] * inv;
}

// ---------------------------------------------------------------------------
// gating GEMM (proven): 128x128x64, global_load_lds both operands, 4 blk/CU
// ---------------------------------------------------------------------------
template<bool DO_ELU>
__global__ __launch_bounds__(256, 4)
void gemm_bf16(const unsigned short* __restrict__ A,
               const unsigned short* __restrict__ BT,
               const float* __restrict__ bias,
               unsigned short* __restrict__ Out,
               int N, int ld, int kpart) {
    __shared__ unsigned short As[128 * 64];
    __shared__ unsigned short Bs[128 * 64];
    int ntn = N >> 7;
    int nwg = gridDim.x;
    int bid = blockIdx.x;
    { int cpx = nwg >> 3; bid = (bid & 7) * cpx + (bid >> 3); }
    int tm = bid / ntn, tn = bid - tm * ntn;
    int row0 = tm << 7, col0 = tn << 7;
    int t = threadIdx.x;
    int lane = t & 63;
    int wid = t >> 6;
    int wr = wid >> 1, wc = wid & 1;
    const unsigned short* Ab = A + (size_t)(row0 + wid * 32 + (lane >> 3)) * ld + (lane & 7) * 8;
    const unsigned short* Bb = BT + (size_t)(col0 + wid * 32 + (lane >> 3)) * ld + (lane & 7) * 8;
    unsigned short* Asd = &As[wid * 32 * 64];
    unsigned short* Bsd = &Bs[wid * 32 * 64];
    f32x4 acc[4][4];
    #pragma unroll
    for (int i = 0; i < 4; ++i)
        #pragma unroll
        for (int j = 0; j < 4; ++j) acc[i][j] = (f32x4){0.f, 0.f, 0.f, 0.f};
    int nkt = kpart >> 6;
    for (int kt = 0; kt < nkt; ++kt) {
        size_t ko = (size_t)kt << 6;
        #pragma unroll
        for (int q = 0; q < 4; ++q) {
            gload_lds16(Ab + (size_t)(q * 8) * ld + ko, Asd + q * 8 * 64);
            gload_lds16(Bb + (size_t)(q * 8) * ld + ko, Bsd + q * 8 * 64);
        }
        __syncthreads();
        #pragma unroll
        for (int kk = 0; kk < 2; ++kk) {
            bf16x8 af[4], bfr[4];
            #pragma unroll
            for (int m = 0; m < 4; ++m)
                af[m] = *(const bf16x8*)(&As[(wr * 64 + m * 16 + (lane & 15)) * 64 + kk * 32 + (lane >> 4) * 8]);
            #pragma unroll
            for (int n = 0; n < 4; ++n)
                bfr[n] = *(const bf16x8*)(&Bs[(wc * 64 + n * 16 + (lane & 15)) * 64 + kk * 32 + (lane >> 4) * 8]);
            #pragma unroll
            for (int m = 0; m < 4; ++m)
                #pragma unroll
                for (int n = 0; n < 4; ++n)
                    acc[m][n] = __builtin_amdgcn_mfma_f32_16x16x32_bf16(af[m], bfr[n], acc[m][n], 0, 0, 0);
        }
        __syncthreads();
    }
    #pragma unroll
    for (int m = 0; m < 4; ++m) {
        int rbase = row0 + wr * 64 + m * 16 + ((lane >> 4) << 2);
        #pragma unroll
        for (int n = 0; n < 4; ++n) {
            int cg = col0 + wc * 64 + n * 16 + (lane & 15);
            float bv = bias[cg];
            #pragma unroll
            for (int r2 = 0; r2 < 4; ++r2) {
                float v = acc[m][n][r2] + bv;
                if (DO_ELU) v = v > 0.f ? v : (__expf(v) - 1.f);
                Out[(size_t)(rbase + r2) * N + cg] = f2bf(v);
            }
        }
    }
}

// ---------------------------------------------------------------------------
// Fused MoE GEMM (r20, best-ever: 125.3 us/mid-layer): 256x256-virtual tile,
// 8 waves (wave = 128x64v), BK=32 slots, 4-slot LDS ring (128 KB), swizzled
// staging/reads, swapped-operand MFMA. Per iteration (2 slots): stage
// s+2,s+3 -> VM8 (counted) -> barrier -> merged 2-slot compute with cross-
// slot SGB-pinned reads (1-2 reads per 4-MFMA block, 16-MFMA read->use
// distance). 2D XCD map (FETCH 94 MB).
// Epilogue: in-register expert mix -> LDS fp32 partials -> y store direct.
// ---------------------------------------------------------------------------
template<bool DO_ELU, bool OUT_F32>
__global__ __launch_bounds__(512, 1)
void gemm_fused(const unsigned short* __restrict__ A,   // [8192, K]
                const unsigned short* __restrict__ BT,  // [8*dout, K]
                const float* __restrict__ coeffs,       // [8192, 8]
                const float* __restrict__ bias,         // [8*dout]
                void* __restrict__ Out,                 // [8192, dout]
                int K, int dout) {
    __shared__ unsigned short lds[65536];           // 4 x (A 8192 + B 8192)

    // 2D concurrency-aware XCD mapping (r12 proven)
    int bid = blockIdx.x;
    int x = bid & 7;
    int i = bid >> 3;
    int within = i & 15;
    int tm = x * 4 + (within & 3);
    int tn = (i >> 4) * 4 + (within >> 2);
    int row0 = tm << 8;
    int c0 = tn << 5;
    int nkt = K >> 5;

    int t = threadIdx.x;
    int lane = t & 63, wid = t >> 6;
    int wm = wid >> 2, wn = wid & 3;                 // 2x4 waves, each 128x64
    int q = lane >> 4;
    int l15 = lane & 15;

    // fragment ds_read offsets (ushort units), swizzled
    int aoff[8], boff[4];
    #pragma unroll
    for (int m = 0; m < 8; ++m) {
        int row = wm * 128 + m * 16 + l15;
        aoff[m] = row * 32 + ((q ^ ((row >> 1) & 3)) << 3);
    }
    #pragma unroll
    for (int n = 0; n < 4; ++n) {
        int row = wn * 64 + n * 16 + l15;
        boff[n] = 8192 + row * 32 + ((q ^ ((row >> 1) & 3)) << 3);
    }

    // stage source (per-thread, inverse-swizzled column)
    int srow = t >> 2;
    int scol = ((t & 3) ^ ((t >> 3) & 3)) * 8;
    const unsigned short* Asrc = A + (size_t)(row0 + srow) * K + scol;
    // virtual B rows: vr -> BT row (vr>>5)*dout + c0 + (vr&31)
    int br0 = (srow >> 5) * dout + c0 + (srow & 31);            // vr = srow
    int br1 = ((srow + 128) >> 5) * dout + c0 + (srow & 31);    // vr = srow+128
    const unsigned short* Bsrc0 = BT + (size_t)br0 * K + scol;
    const unsigned short* Bsrc1 = BT + (size_t)br1 * K + scol;
    int wdst = wid * 512;                            // wave-uniform dest term

    f32x4 acc[8][4];
    #pragma unroll
    for (int m = 0; m < 8; ++m)
        #pragma unroll
        for (int n = 0; n < 4; ++n) acc[m][n] = (f32x4){0.f, 0.f, 0.f, 0.f};

    // ---- prologue: stage slots 0, 1 ----
    #pragma unroll
    for (int S = 0; S < 2; ++S) {
        gload_lds16(Asrc + S * 32,                   &lds[S * 16384 + wdst]);
        gload_lds16(Asrc + (size_t)128 * K + S * 32, &lds[S * 16384 + 4096 + wdst]);
        gload_lds16(Bsrc0 + S * 32,                  &lds[S * 16384 + 8192 + wdst]);
        gload_lds16(Bsrc1 + S * 32,                  &lds[S * 16384 + 12288 + wdst]);
    }

    for (int s = 0; s < nkt; s += 2) {               // nkt even (18 or 32)
        int sbA = (s & 3) << 14;
        int sbB = ((s + 1) & 3) << 14;
        bool st = (s + 2) < nkt;

        // stage s+2, s+3 FIRST (targets bufs read at s-2: safe; issues early)
        if (st) {
            int rbA = ((s + 2) & 3) << 14;
            int rbB = ((s + 3) & 3) << 14;
            int koA = (s + 2) << 5;
            int koB = (s + 3) << 5;
            gload_lds16(Asrc + koA,                   &lds[rbA + wdst]);
            gload_lds16(Asrc + (size_t)128 * K + koA, &lds[rbA + 4096 + wdst]);
            gload_lds16(Bsrc0 + koA,                  &lds[rbA + 8192 + wdst]);
            gload_lds16(Bsrc1 + koA,                  &lds[rbA + 12288 + wdst]);
            gload_lds16(Asrc + koB,                   &lds[rbB + wdst]);
            gload_lds16(Asrc + (size_t)128 * K + koB, &lds[rbB + 4096 + wdst]);
            gload_lds16(Bsrc0 + koB,                  &lds[rbB + 8192 + wdst]);
            gload_lds16(Bsrc1 + koB,                  &lds[rbB + 12288 + wdst]);
        }
        SB0;
        if (st) { VM8; } else { VM0; }               // drain s,s+1; keep s+2,s+3
        SB0;
        BAR;                                         // all waves' s,s+1 published
        SB0;

        // ---- merged 2-slot compute with cross-slot pinned reads ----
        {
            bf16x8 bA[4], aA[8], bB[4], aB[8];
            // pre-reads: B(s) + A0-3(s)
            #pragma unroll
            for (int n = 0; n < 4; ++n)
                bA[n] = *(const bf16x8*)(&lds[sbA + boff[n]]);
            #pragma unroll
            for (int m = 0; m < 4; ++m)
                aA[m] = *(const bf16x8*)(&lds[sbA + aoff[m]]);
            SGB_DS(8);
            __builtin_amdgcn_s_setprio(1);
            // slot s m-blocks
            #pragma unroll
            for (int m = 0; m < 8; ++m) {
                if (m < 4) {
                    aA[m + 4] = *(const bf16x8*)(&lds[sbA + aoff[m + 4]]);
                } else {
                    bB[m - 4] = *(const bf16x8*)(&lds[sbB + boff[m - 4]]);
                    aB[m - 4] = *(const bf16x8*)(&lds[sbB + aoff[m - 4]]);
                }
                #pragma unroll
                for (int n = 0; n < 4; ++n)
                    acc[m][n] = __builtin_amdgcn_mfma_f32_16x16x32_bf16(bA[n], aA[m], acc[m][n], 0, 0, 0);
                if (m < 4) { SGB_DS(1); } else { SGB_DS(2); }
                SGB_MFMA(4);
            }
            // slot s+1 m-blocks
            #pragma unroll
            for (int m = 0; m < 8; ++m) {
                if (m < 4) {
                    aB[m + 4] = *(const bf16x8*)(&lds[sbB + aoff[m + 4]]);
                }
                #pragma unroll
                for (int n = 0; n < 4; ++n)
                    acc[m][n] = __builtin_amdgcn_mfma_f32_16x16x32_bf16(bB[n], aB[m], acc[m][n], 0, 0, 0);
                if (m < 4) { SGB_DS(1); }
                SGB_MFMA(4);
            }
            __builtin_amdgcn_s_setprio(0);
        }
        SB0;
    }

    // ======== epilogue phase 1: per-wave expert mix -> LDS fp32 partials ===
    float* plds = (float*)lds;                       // 8 regions x [128][32] f32
    __syncthreads();                                 // ring fully consumed
    {
        int e0 = 2 * wn, e1 = e0 + 1;
        f32x4 b0h[2], b1h[2];
        #pragma unroll
        for (int h = 0; h < 2; ++h) {
            float4 u0 = *(const float4*)(bias + e0 * dout + c0 + h * 16 + q * 4);
            float4 u1 = *(const float4*)(bias + e1 * dout + c0 + h * 16 + q * 4);
            b0h[h] = (f32x4){u0.x, u0.y, u0.z, u0.w};
            b1h[h] = (f32x4){u1.x, u1.y, u1.z, u1.w};
        }
        float* preg = plds + (wid << 12);
        #pragma unroll
        for (int m = 0; m < 8; ++m) {
            int grow = row0 + wm * 128 + m * 16 + l15;
            float c8 = coeffs[(size_t)grow * 8 + e0];
            float c9 = coeffs[(size_t)grow * 8 + e1];
            #pragma unroll
            for (int h = 0; h < 2; ++h) {
                f32x4 z0 = acc[m][h];
                f32x4 z1 = acc[m][h + 2];
                f32x4 p;
                #pragma unroll
                for (int r = 0; r < 4; ++r)
                    p[r] = c8 * (z0[r] + b0h[h][r]) + c9 * (z1[r] + b1h[h][r]);
                int row = m * 16 + l15;
                int slot = (h * 4 + q) ^ (row & 7);
                *(f32x4*)(preg + row * 32 + (slot << 2)) = p;
            }
        }
    }
    __syncthreads();

    // ======== epilogue phase 2: sum 4 wn-partials, act, store ==============
    {
        int r2 = t >> 1;                             // tile row 0..255
        int ch = t & 1;                              // col half (16 cols)
        int wmr = r2 >> 7;
        int rr = r2 & 127;
        int sw = rr & 7;
        size_t obase = (size_t)(row0 + r2) * dout + c0 + ch * 16;
        #pragma unroll
        for (int sl = 0; sl < 4; ++sl) {
            int L = ch * 4 + sl;
            int phys = L ^ sw;
            f32x4 sum = (f32x4){0.f, 0.f, 0.f, 0.f};
            #pragma unroll
            for (int w2 = 0; w2 < 4; ++w2) {
                const f32x4 v = *(const f32x4*)(plds + (((wmr << 2) + w2) << 12) + rr * 32 + (phys << 2));
                sum[0] += v[0]; sum[1] += v[1]; sum[2] += v[2]; sum[3] += v[3];
            }
            if (DO_ELU) {
                #pragma unroll
                for (int r = 0; r < 4; ++r)
                    sum[r] = sum[r] > 0.f ? sum[r] : (__expf(sum[r]) - 1.f);
            }
            if (OUT_F32) {
                float4 o = {sum[0], sum[1], sum[2], sum[3]};
                *(float4*)((float*)Out + obase + sl * 4) = o;
            } else {
                ushort4 o;
                o.x = f2bf(sum[0]); o.y = f2bf(sum[1]);
                o.z = f2bf(sum[2]); o.w = f2bf(sum[3]);
                *(ushort4*)((unsigned short*)Out + obase + sl * 4) = o;
            }
        }
    }
}

// ---------------------------------------------------------------------------
extern "C" void kernel_launch(void* const* d_in, const int* in_sizes, int n_in,
                              void* d_out, int out_size, void* d_ws, size_t ws_size,
                              hipStream_t stream) {
    const float* motion  = (const float*)d_in[0];
    const float* command = (const float*)d_in[1];
    const float* g_w1 = (const float*)d_in[2];
    const float* g_b1 = (const float*)d_in[3];
    const float* g_w2 = (const float*)d_in[4];
    const float* g_b2 = (const float*)d_in[5];
    const float* g_w3 = (const float*)d_in[6];
    const float* g_b3 = (const float*)d_in[7];
    const float* w[6]  = {(const float*)d_in[8],  (const float*)d_in[10],
                          (const float*)d_in[12], (const float*)d_in[14],
                          (const float*)d_in[16], (const float*)d_in[18]};
    const float* bb[6] = {(const float*)d_in[9],  (const float*)d_in[11],
                          (const float*)d_in[13], (const float*)d_in[15],
                          (const float*)d_in[17], (const float*)d_in[19]};

    char* ws = (char*)d_ws;
    unsigned short* xc0  = (unsigned short*)ws;                   //  9,437,184
    unsigned short* actA = (unsigned short*)(ws + 9437184);       // 16,777,216
    unsigned short* actB = (unsigned short*)(ws + 26214400);      // 16,777,216
    float* coeffs        = (float*)(ws + 42991616);               //    262,144
    unsigned short* wTg1 = (unsigned short*)(ws + 43253760);      //  1,179,648
    unsigned short* wTg2 = (unsigned short*)(ws + 44433408);      //  2,097,152
    unsigned short* wT0  = (unsigned short*)(ws + 46530560);      //  9,437,184
    unsigned short* wT1  = (unsigned short*)(ws + 55967744);      // 16,777,216
    unsigned short* wT2  = (unsigned short*)(ws + 72744960);      // 16,777,216
    unsigned short* wT3  = (unsigned short*)(ws + 89522176);      // 16,777,216
    unsigned short* wT4  = (unsigned short*)(ws + 106299392);     // 16,777,216
    unsigned short* wT5  = (unsigned short*)(ws + 123076608);     //  8,388,608
    unsigned short* wTL[6] = {wT0, wT1, wT2, wT3, wT4, wT5};

    // 1. ALL weight transposes in ONE dispatch (independent of activations)
    transpose_all<<<10768, 256, 0, stream>>>(
        g_w1, g_w2, w[0], w[1], w[2], w[3], w[4], w[5],
        wTg1, wTg2, wT0, wT1, wT2, wT3, wT4, wT5);

    // 2. concat + convert input
    concat_cvt<<<4608, 256, 0, stream>>>(motion, command, xc0);

    // 3. gating network
    gemm_bf16<true><<<512, 256, 0, stream>>>(xc0, wTg1, g_b1, actA, 1024, 576, 576);
    gemm_bf16<true><<<512, 256, 0, stream>>>(actA, wTg2, g_b2, actB, 1024, 1024, 1024);
    gating_kernel<<<2048, 256, 0, stream>>>(actB, g_w3, g_b3, coeffs);

    // 4. MoE layer 0: K=576 (nkt=18), dout=1024 -> actA
    gemm_fused<true, false><<<1024, 512, 0, stream>>>(
        xc0, wT0, coeffs, bb[0], actA, 576, 1024);

    // 5. MoE layers 1..4: K=1024 (nkt=32), dout=1024, ping-pong actA/actB
    unsigned short* bufs[2] = {actA, actB};
    for (int l = 1; l <= 4; ++l) {
        unsigned short* in  = bufs[(l + 1) & 1];
        unsigned short* out = bufs[l & 1];
        gemm_fused<true, false><<<1024, 512, 0, stream>>>(
            in, wTL[l], coeffs, bb[l], out, 1024, 1024);
    }

    // 6. MoE layer 5: K=1024, dout=512, fp32 out
    gemm_fused<false, true><<<512, 512, 0, stream>>>(
        actA, wT5, coeffs, bb[5], d_out, 1024, 512);
}

// Round 22
// 674.228 us; speedup vs baseline: 1.2673x; 1.0058x over previous
//
#include <hip/hip_runtime.h>
#include <hip/hip_bf16.h>

typedef __attribute__((ext_vector_type(8))) short bf16x8;
typedef __attribute__((ext_vector_type(4))) float f32x4;

__device__ __forceinline__ float bf2f(unsigned short u) {
    union { unsigned int i; float f; } v; v.i = ((unsigned int)u) << 16; return v.f;
}
__device__ __forceinline__ unsigned short f2bf(float f) {
    union { float f; unsigned int i; } v; v.f = f;
    unsigned int x = v.i;
    return (unsigned short)((x + 0x7FFFu + ((x >> 16) & 1u)) >> 16);
}

__device__ __forceinline__ void gload_lds16(const unsigned short* g, unsigned short* l) {
    __builtin_amdgcn_global_load_lds(
        (const __attribute__((address_space(1))) unsigned int*)g,
        (__attribute__((address_space(3))) unsigned int*)l,
        16, 0, 0);
}

#define VM8  asm volatile("s_waitcnt vmcnt(8)" ::: "memory")
#define VM0  asm volatile("s_waitcnt vmcnt(0)" ::: "memory")
#define SB0  __builtin_amdgcn_sched_barrier(0)
#define BAR  __builtin_amdgcn_s_barrier()
#define SGB_DS(n)   __builtin_amdgcn_sched_group_barrier(0x100, (n), 0)
#define SGB_MFMA(n) __builtin_amdgcn_sched_group_barrier(0x008, (n), 0)

// ---------------------------------------------------------------------------
// device transpose tile worker: fp32 [K,N] (+e offset) -> bf16 [N,K]
// ---------------------------------------------------------------------------
__device__ __forceinline__ void transp_tile(const float* in, unsigned short* out,
                                            int K, int N, int tpe, int rel, int t) {
    __shared__ unsigned short tile[64][72];
    int e = rel / tpe, r = rel % tpe;
    in  += (size_t)e * K * N;
    out += (size_t)e * N * K;
    int nbn = N / 64;
    int k0 = (r / nbn) * 64;
    int n0 = (r % nbn) * 64;
    int tx = t & 63, ty = t >> 6;
    #pragma unroll
    for (int rr = 0; rr < 16; ++rr) {
        int kr = ty + rr * 4;
        tile[kr][tx] = f2bf(in[(size_t)(k0 + kr) * N + n0 + tx]);
    }
    __syncthreads();
    int txh = t & 31, tyh = t >> 5;
    #pragma unroll
    for (int rr = 0; rr < 8; ++rr) {
        int nr = tyh + rr * 8;
        unsigned int vlo = tile[2 * txh][nr];
        unsigned int vhi = tile[2 * txh + 1][nr];
        unsigned int* o32 = (unsigned int*)(out + (size_t)(n0 + nr) * K + k0);
        o32[txh] = vlo | (vhi << 16);
    }
}

// ---------------------------------------------------------------------------
// ONE prep dispatch: ALL 8 weight transposes + input concat/convert.
// [0,144) g_w1 | [144,400) g_w2 | [400,1552) w0 | [1552,3600) w1 |
// [3600,5648) w2 | [5648,7696) w3 | [7696,9744) w4 | [9744,10768) w5 |
// [10768,15376) concat(motion,command) -> xc0
// ---------------------------------------------------------------------------
__global__ __launch_bounds__(256)
void prep_all(const float* __restrict__ g_w1, const float* __restrict__ g_w2,
              const float* __restrict__ w0, const float* __restrict__ w1,
              const float* __restrict__ w2, const float* __restrict__ w3,
              const float* __restrict__ w4, const float* __restrict__ w5,
              const float* __restrict__ motion, const float* __restrict__ command,
              unsigned short* __restrict__ tg1, unsigned short* __restrict__ tg2,
              unsigned short* __restrict__ t0, unsigned short* __restrict__ t1,
              unsigned short* __restrict__ t2, unsigned short* __restrict__ t3,
              unsigned short* __restrict__ t4, unsigned short* __restrict__ t5,
              unsigned short* __restrict__ xc0) {
    int b = blockIdx.x;
    int t = threadIdx.x;
    if (b < 144)        transp_tile(g_w1, tg1, 576, 1024, 144, b, t);
    else if (b < 400)   transp_tile(g_w2, tg2, 1024, 1024, 256, b - 144, t);
    else if (b < 1552)  transp_tile(w0, t0, 576, 1024, 144, b - 400, t);
    else if (b < 3600)  transp_tile(w1, t1, 1024, 1024, 256, b - 1552, t);
    else if (b < 5648)  transp_tile(w2, t2, 1024, 1024, 256, b - 3600, t);
    else if (b < 7696)  transp_tile(w3, t3, 1024, 1024, 256, b - 5648, t);
    else if (b < 9744)  transp_tile(w4, t4, 1024, 1024, 256, b - 7696, t);
    else if (b < 10768) transp_tile(w5, t5, 1024, 512, 128, b - 9744, t);
    else {
        int id = (b - 10768) * 256 + t;              // 8192*144 quads
        int row = id / 144, qd = id % 144;
        float4 v;
        if (qd < 128) v = *(const float4*)(motion + (size_t)row * 512 + qd * 4);
        else          v = *(const float4*)(command + (size_t)row * 64 + (qd - 128) * 4);
        ushort4 o;
        o.x = f2bf(v.x); o.y = f2bf(v.y); o.z = f2bf(v.z); o.w = f2bf(v.w);
        *(ushort4*)(xc0 + (size_t)row * 576 + qd * 4) = o;
    }
}

// ---------------------------------------------------------------------------
// gating final: coeffs = softmax(g2 @ w3 + b3)
// ---------------------------------------------------------------------------
__global__ __launch_bounds__(256) void gating_kernel(
    const unsigned short* __restrict__ g2,
    const float* __restrict__ w3, const float* __restrict__ b3,
    float* __restrict__ coeffs) {
    __shared__ float w3s[8][1024];
    int t = threadIdx.x;
    for (int i = t; i < 1024; i += 256) {
        #pragma unroll
        for (int e = 0; e < 8; ++e) w3s[e][i] = w3[(size_t)i * 8 + e];
    }
    __syncthreads();
    int lane = t & 63, wv = t >> 6;
    int row = blockIdx.x * 4 + wv;
    const unsigned short* xr = g2 + (size_t)row * 1024;
    float acc[8];
    #pragma unroll
    for (int e = 0; e < 8; ++e) acc[e] = 0.f;
    for (int it = 0; it < 16; ++it) {
        float xv = bf2f(xr[lane + it * 64]);
        #pragma unroll
        for (int e = 0; e < 8; ++e) acc[e] += xv * w3s[e][lane + it * 64];
    }
    #pragma unroll
    for (int e = 0; e < 8; ++e) {
        float v = acc[e];
        #pragma unroll
        for (int off = 32; off; off >>= 1) v += __shfl_xor(v, off);
        acc[e] = v + b3[e];
    }
    float mx = acc[0];
    #pragma unroll
    for (int e = 1; e < 8; ++e) mx = fmaxf(mx, acc[e]);
    float s = 0.f;
    #pragma unroll
    for (int e = 0; e < 8; ++e) { acc[e] = __expf(acc[e] - mx); s += acc[e]; }
    float inv = 1.f / s;
    if (lane < 8) coeffs[(size_t)row * 8 + lane] = acc[lane] * inv;
}

// ---------------------------------------------------------------------------
// gating GEMM (proven): 128x128x64, global_load_lds both operands, 4 blk/CU
// ---------------------------------------------------------------------------
template<bool DO_ELU>
__global__ __launch_bounds__(256, 4)
void gemm_bf16(const unsigned short* __restrict__ A,
               const unsigned short* __restrict__ BT,
               const float* __restrict__ bias,
               unsigned short* __restrict__ Out,
               int N, int ld, int kpart) {
    __shared__ unsigned short As[128 * 64];
    __shared__ unsigned short Bs[128 * 64];
    int ntn = N >> 7;
    int nwg = gridDim.x;
    int bid = blockIdx.x;
    { int cpx = nwg >> 3; bid = (bid & 7) * cpx + (bid >> 3); }
    int tm = bid / ntn, tn = bid - tm * ntn;
    int row0 = tm << 7, col0 = tn << 7;
    int t = threadIdx.x;
    int lane = t & 63;
    int wid = t >> 6;
    int wr = wid >> 1, wc = wid & 1;
    const unsigned short* Ab = A + (size_t)(row0 + wid * 32 + (lane >> 3)) * ld + (lane & 7) * 8;
    const unsigned short* Bb = BT + (size_t)(col0 + wid * 32 + (lane >> 3)) * ld + (lane & 7) * 8;
    unsigned short* Asd = &As[wid * 32 * 64];
    unsigned short* Bsd = &Bs[wid * 32 * 64];
    f32x4 acc[4][4];
    #pragma unroll
    for (int i = 0; i < 4; ++i)
        #pragma unroll
        for (int j = 0; j < 4; ++j) acc[i][j] = (f32x4){0.f, 0.f, 0.f, 0.f};
    int nkt = kpart >> 6;
    for (int kt = 0; kt < nkt; ++kt) {
        size_t ko = (size_t)kt << 6;
        #pragma unroll
        for (int q = 0; q < 4; ++q) {
            gload_lds16(Ab + (size_t)(q * 8) * ld + ko, Asd + q * 8 * 64);
            gload_lds16(Bb + (size_t)(q * 8) * ld + ko, Bsd + q * 8 * 64);
        }
        __syncthreads();
        #pragma unroll
        for (int kk = 0; kk < 2; ++kk) {
            bf16x8 af[4], bfr[4];
            #pragma unroll
            for (int m = 0; m < 4; ++m)
                af[m] = *(const bf16x8*)(&As[(wr * 64 + m * 16 + (lane & 15)) * 64 + kk * 32 + (lane >> 4) * 8]);
            #pragma unroll
            for (int n = 0; n < 4; ++n)
                bfr[n] = *(const bf16x8*)(&Bs[(wc * 64 + n * 16 + (lane & 15)) * 64 + kk * 32 + (lane >> 4) * 8]);
            #pragma unroll
            for (int m = 0; m < 4; ++m)
                #pragma unroll
                for (int n = 0; n < 4; ++n)
                    acc[m][n] = __builtin_amdgcn_mfma_f32_16x16x32_bf16(af[m], bfr[n], acc[m][n], 0, 0, 0);
        }
        __syncthreads();
    }
    #pragma unroll
    for (int m = 0; m < 4; ++m) {
        int rbase = row0 + wr * 64 + m * 16 + ((lane >> 4) << 2);
        #pragma unroll
        for (int n = 0; n < 4; ++n) {
            int cg = col0 + wc * 64 + n * 16 + (lane & 15);
            float bv = bias[cg];
            #pragma unroll
            for (int r2 = 0; r2 < 4; ++r2) {
                float v = acc[m][n][r2] + bv;
                if (DO_ELU) v = v > 0.f ? v : (__expf(v) - 1.f);
                Out[(size_t)(rbase + r2) * N + cg] = f2bf(v);
            }
        }
    }
}

// ---------------------------------------------------------------------------
// Fused MoE GEMM (r20/r21, best: 125 us/mid-layer): 256x256-virtual tile,
// 8 waves (wave = 128x64v), BK=32 slots, 4-slot LDS ring (128 KB), swizzled
// staging/reads, swapped-operand MFMA. Per iteration (2 slots): stage
// s+2,s+3 -> VM8 (counted) -> barrier -> merged 2-slot compute with cross-
// slot SGB-pinned reads (1-2 reads per 4-MFMA block, 16-MFMA read->use
// distance). 2D XCD map (FETCH ~95 MB).
// Epilogue: in-register expert mix -> LDS fp32 partials -> y store direct.
// ---------------------------------------------------------------------------
template<bool DO_ELU, bool OUT_F32>
__global__ __launch_bounds__(512, 1)
void gemm_fused(const unsigned short* __restrict__ A,   // [8192, K]
                const unsigned short* __restrict__ BT,  // [8*dout, K]
                const float* __restrict__ coeffs,       // [8192, 8]
                const float* __restrict__ bias,         // [8*dout]
                void* __restrict__ Out,                 // [8192, dout]
                int K, int dout) {
    __shared__ unsigned short lds[65536];           // 4 x (A 8192 + B 8192)

    // 2D concurrency-aware XCD mapping (r12 proven)
    int bid = blockIdx.x;
    int x = bid & 7;
    int i = bid >> 3;
    int within = i & 15;
    int tm = x * 4 + (within & 3);
    int tn = (i >> 4) * 4 + (within >> 2);
    int row0 = tm << 8;
    int c0 = tn << 5;
    int nkt = K >> 5;

    int t = threadIdx.x;
    int lane = t & 63, wid = t >> 6;
    int wm = wid >> 2, wn = wid & 3;                 // 2x4 waves, each 128x64
    int q = lane >> 4;
    int l15 = lane & 15;

    // fragment ds_read offsets (ushort units), swizzled
    int aoff[8], boff[4];
    #pragma unroll
    for (int m = 0; m < 8; ++m) {
        int row = wm * 128 + m * 16 + l15;
        aoff[m] = row * 32 + ((q ^ ((row >> 1) & 3)) << 3);
    }
    #pragma unroll
    for (int n = 0; n < 4; ++n) {
        int row = wn * 64 + n * 16 + l15;
        boff[n] = 8192 + row * 32 + ((q ^ ((row >> 1) & 3)) << 3);
    }

    // stage source (per-thread, inverse-swizzled column)
    int srow = t >> 2;
    int scol = ((t & 3) ^ ((t >> 3) & 3)) * 8;
    const unsigned short* Asrc = A + (size_t)(row0 + srow) * K + scol;
    // virtual B rows: vr -> BT row (vr>>5)*dout + c0 + (vr&31)
    int br0 = (srow >> 5) * dout + c0 + (srow & 31);            // vr = srow
    int br1 = ((srow + 128) >> 5) * dout + c0 + (srow & 31);    // vr = srow+128
    const unsigned short* Bsrc0 = BT + (size_t)br0 * K + scol;
    const unsigned short* Bsrc1 = BT + (size_t)br1 * K + scol;
    int wdst = wid * 512;                            // wave-uniform dest term

    f32x4 acc[8][4];
    #pragma unroll
    for (int m = 0; m < 8; ++m)
        #pragma unroll
        for (int n = 0; n < 4; ++n) acc[m][n] = (f32x4){0.f, 0.f, 0.f, 0.f};

    // ---- prologue: stage slots 0, 1 ----
    #pragma unroll
    for (int S = 0; S < 2; ++S) {
        gload_lds16(Asrc + S * 32,                   &lds[S * 16384 + wdst]);
        gload_lds16(Asrc + (size_t)128 * K + S * 32, &lds[S * 16384 + 4096 + wdst]);
        gload_lds16(Bsrc0 + S * 32,                  &lds[S * 16384 + 8192 + wdst]);
        gload_lds16(Bsrc1 + S * 32,                  &lds[S * 16384 + 12288 + wdst]);
    }

    for (int s = 0; s < nkt; s += 2) {               // nkt even (18 or 32)
        int sbA = (s & 3) << 14;
        int sbB = ((s + 1) & 3) << 14;
        bool st = (s + 2) < nkt;

        // stage s+2, s+3 FIRST (targets bufs read at s-2: safe; issues early)
        if (st) {
            int rbA = ((s + 2) & 3) << 14;
            int rbB = ((s + 3) & 3) << 14;
            int koA = (s + 2) << 5;
            int koB = (s + 3) << 5;
            gload_lds16(Asrc + koA,                   &lds[rbA + wdst]);
            gload_lds16(Asrc + (size_t)128 * K + koA, &lds[rbA + 4096 + wdst]);
            gload_lds16(Bsrc0 + koA,                  &lds[rbA + 8192 + wdst]);
            gload_lds16(Bsrc1 + koA,                  &lds[rbA + 12288 + wdst]);
            gload_lds16(Asrc + koB,                   &lds[rbB + wdst]);
            gload_lds16(Asrc + (size_t)128 * K + koB, &lds[rbB + 4096 + wdst]);
            gload_lds16(Bsrc0 + koB,                  &lds[rbB + 8192 + wdst]);
            gload_lds16(Bsrc1 + koB,                  &lds[rbB + 12288 + wdst]);
        }
        SB0;
        if (st) { VM8; } else { VM0; }               // drain s,s+1; keep s+2,s+3
        SB0;
        BAR;                                         // all waves' s,s+1 published
        SB0;

        // ---- merged 2-slot compute with cross-slot pinned reads ----
        {
            bf16x8 bA[4], aA[8], bB[4], aB[8];
            // pre-reads: B(s) + A0-3(s)
            #pragma unroll
            for (int n = 0; n < 4; ++n)
                bA[n] = *(const bf16x8*)(&lds[sbA + boff[n]]);
            #pragma unroll
            for (int m = 0; m < 4; ++m)
                aA[m] = *(const bf16x8*)(&lds[sbA + aoff[m]]);
            SGB_DS(8);
            __builtin_amdgcn_s_setprio(1);
            // slot s m-blocks
            #pragma unroll
            for (int m = 0; m < 8; ++m) {
                if (m < 4) {
                    aA[m + 4] = *(const bf16x8*)(&lds[sbA + aoff[m + 4]]);
                } else {
                    bB[m - 4] = *(const bf16x8*)(&lds[sbB + boff[m - 4]]);
                    aB[m - 4] = *(const bf16x8*)(&lds[sbB + aoff[m - 4]]);
                }
                #pragma unroll
                for (int n = 0; n < 4; ++n)
                    acc[m][n] = __builtin_amdgcn_mfma_f32_16x16x32_bf16(bA[n], aA[m], acc[m][n], 0, 0, 0);
                if (m < 4) { SGB_DS(1); } else { SGB_DS(2); }
                SGB_MFMA(4);
            }
            // slot s+1 m-blocks
            #pragma unroll
            for (int m = 0; m < 8; ++m) {
                if (m < 4) {
                    aB[m + 4] = *(const bf16x8*)(&lds[sbB + aoff[m + 4]]);
                }
                #pragma unroll
                for (int n = 0; n < 4; ++n)
                    acc[m][n] = __builtin_amdgcn_mfma_f32_16x16x32_bf16(bB[n], aB[m], acc[m][n], 0, 0, 0);
                if (m < 4) { SGB_DS(1); }
                SGB_MFMA(4);
            }
            __builtin_amdgcn_s_setprio(0);
        }
        SB0;
    }

    // ======== epilogue phase 1: per-wave expert mix -> LDS fp32 partials ===
    float* plds = (float*)lds;                       // 8 regions x [128][32] f32
    __syncthreads();                                 // ring fully consumed
    {
        int e0 = 2 * wn, e1 = e0 + 1;
        f32x4 b0h[2], b1h[2];
        #pragma unroll
        for (int h = 0; h < 2; ++h) {
            float4 u0 = *(const float4*)(bias + e0 * dout + c0 + h * 16 + q * 4);
            float4 u1 = *(const float4*)(bias + e1 * dout + c0 + h * 16 + q * 4);
            b0h[h] = (f32x4){u0.x, u0.y, u0.z, u0.w};
            b1h[h] = (f32x4){u1.x, u1.y, u1.z, u1.w};
        }
        float* preg = plds + (wid << 12);
        #pragma unroll
        for (int m = 0; m < 8; ++m) {
            int grow = row0 + wm * 128 + m * 16 + l15;
            float c8 = coeffs[(size_t)grow * 8 + e0];
            float c9 = coeffs[(size_t)grow * 8 + e1];
            #pragma unroll
            for (int h = 0; h < 2; ++h) {
                f32x4 z0 = acc[m][h];
                f32x4 z1 = acc[m][h + 2];
                f32x4 p;
                #pragma unroll
                for (int r = 0; r < 4; ++r)
                    p[r] = c8 * (z0[r] + b0h[h][r]) + c9 * (z1[r] + b1h[h][r]);
                int row = m * 16 + l15;
                int slot = (h * 4 + q) ^ (row & 7);
                *(f32x4*)(preg + row * 32 + (slot << 2)) = p;
            }
        }
    }
    __syncthreads();

    // ======== epilogue phase 2: sum 4 wn-partials, act, store ==============
    {
        int r2 = t >> 1;                             // tile row 0..255
        int ch = t & 1;                              // col half (16 cols)
        int wmr = r2 >> 7;
        int rr = r2 & 127;
        int sw = rr & 7;
        size_t obase = (size_t)(row0 + r2) * dout + c0 + ch * 16;
        #pragma unroll
        for (int sl = 0; sl < 4; ++sl) {
            int L = ch * 4 + sl;
            int phys = L ^ sw;
            f32x4 sum = (f32x4){0.f, 0.f, 0.f, 0.f};
            #pragma unroll
            for (int w2 = 0; w2 < 4; ++w2) {
                const f32x4 v = *(const f32x4*)(plds + (((wmr << 2) + w2) << 12) + rr * 32 + (phys << 2));
                sum[0] += v[0]; sum[1] += v[1]; sum[2] += v[2]; sum[3] += v[3];
            }
            if (DO_ELU) {
                #pragma unroll
                for (int r = 0; r < 4; ++r)
                    sum[r] = sum[r] > 0.f ? sum[r] : (__expf(sum[r]) - 1.f);
            }
            if (OUT_F32) {
                float4 o = {sum[0], sum[1], sum[2], sum[3]};
                *(float4*)((float*)Out + obase + sl * 4) = o;
            } else {
                ushort4 o;
                o.x = f2bf(sum[0]); o.y = f2bf(sum[1]);
                o.z = f2bf(sum[2]); o.w = f2bf(sum[3]);
                *(ushort4*)((unsigned short*)Out + obase + sl * 4) = o;
            }
        }
    }
}

// ---------------------------------------------------------------------------
extern "C" void kernel_launch(void* const* d_in, const int* in_sizes, int n_in,
                              void* d_out, int out_size, void* d_ws, size_t ws_size,
                              hipStream_t stream) {
    const float* motion  = (const float*)d_in[0];
    const float* command = (const float*)d_in[1];
    const float* g_w1 = (const float*)d_in[2];
    const float* g_b1 = (const float*)d_in[3];
    const float* g_w2 = (const float*)d_in[4];
    const float* g_b2 = (const float*)d_in[5];
    const float* g_w3 = (const float*)d_in[6];
    const float* g_b3 = (const float*)d_in[7];
    const float* w[6]  = {(const float*)d_in[8],  (const float*)d_in[10],
                          (const float*)d_in[12], (const float*)d_in[14],
                          (const float*)d_in[16], (const float*)d_in[18]};
    const float* bb[6] = {(const float*)d_in[9],  (const float*)d_in[11],
                          (const float*)d_in[13], (const float*)d_in[15],
                          (const float*)d_in[17], (const float*)d_in[19]};

    char* ws = (char*)d_ws;
    unsigned short* xc0  = (unsigned short*)ws;                   //  9,437,184
    unsigned short* actA = (unsigned short*)(ws + 9437184);       // 16,777,216
    unsigned short* actB = (unsigned short*)(ws + 26214400);      // 16,777,216
    float* coeffs        = (float*)(ws + 42991616);               //    262,144
    unsigned short* wTg1 = (unsigned short*)(ws + 43253760);      //  1,179,648
    unsigned short* wTg2 = (unsigned short*)(ws + 44433408);      //  2,097,152
    unsigned short* wT0  = (unsigned short*)(ws + 46530560);      //  9,437,184
    unsigned short* wT1  = (unsigned short*)(ws + 55967744);      // 16,777,216
    unsigned short* wT2  = (unsigned short*)(ws + 72744960);      // 16,777,216
    unsigned short* wT3  = (unsigned short*)(ws + 89522176);      // 16,777,216
    unsigned short* wT4  = (unsigned short*)(ws + 106299392);     // 16,777,216
    unsigned short* wT5  = (unsigned short*)(ws + 123076608);     //  8,388,608
    unsigned short* wTL[6] = {wT0, wT1, wT2, wT3, wT4, wT5};

    // 1. ONE prep dispatch: all 8 weight transposes + input concat/convert
    prep_all<<<15376, 256, 0, stream>>>(
        g_w1, g_w2, w[0], w[1], w[2], w[3], w[4], w[5], motion, command,
        wTg1, wTg2, wT0, wT1, wT2, wT3, wT4, wT5, xc0);

    // 2. gating network
    gemm_bf16<true><<<512, 256, 0, stream>>>(xc0, wTg1, g_b1, actA, 1024, 576, 576);
    gemm_bf16<true><<<512, 256, 0, stream>>>(actA, wTg2, g_b2, actB, 1024, 1024, 1024);
    gating_kernel<<<2048, 256, 0, stream>>>(actB, g_w3, g_b3, coeffs);

    // 3. MoE layer 0: K=576 (nkt=18), dout=1024 -> actA
    gemm_fused<true, false><<<1024, 512, 0, stream>>>(
        xc0, wT0, coeffs, bb[0], actA, 576, 1024);

    // 4. MoE layers 1..4: K=1024 (nkt=32), dout=1024, ping-pong actA/actB
    unsigned short* bufs[2] = {actA, actB};
    for (int l = 1; l <= 4; ++l) {
        unsigned short* in  = bufs[(l + 1) & 1];
        unsigned short* out = bufs[l & 1];
        gemm_fused<true, false><<<1024, 512, 0, stream>>>(
            in, wTL[l], coeffs, bb[l], out, 1024, 1024);
    }

    // 5. MoE layer 5: K=1024, dout=512, fp32 out
    gemm_fused<false, true><<<512, 512, 0, stream>>>(
        actA, wT5, coeffs, bb[5], d_out, 1024, 512);
}